// Round 6
// baseline (6365.387 us; speedup 1.0000x reference)
//
#include <hip/hip_runtime.h>
#include <math.h>

// ---------------------------------------------------------------------------
// Pointer-network decoder, 50 sequential greedy-decode steps.
// R9 = R3 structure with three targeted changes:
//  - pointer+combine fused (R6's proven inner code) -> 6 dispatches/step,
//    lp_ws roundtrip gone.
//  - glimpse stages its contiguous 50 KB e-slice in LDS once; logits and
//    weighted-sum both read LDS (-52 MB/step global traffic).
//  - GEMM epilogues: bf16 LDS-staged coalesced (pa write-amp fix, measured
//    820 MB -> ~115 MB); fp32 reverted to R3 direct stores (L2-resident
//    outputs, R8 showed the staged fp32 path cost ~2.6 us/step).
// ---------------------------------------------------------------------------

#define S_LEN 50
#define BATCH 512
#define HDIM  512
#define H4    2048
#define BH    (BATCH*HDIM)          // 262144
#define BS    (BATCH*S_LEN)         // 25600
#define KSPQ  4                     // split-K for the small q GEMMs
#define MASK50 0x0003FFFFFFFFFFFFULL

typedef unsigned short u16;
typedef __attribute__((ext_vector_type(8))) short bf16x8;
typedef __attribute__((ext_vector_type(4))) float f32x4;

__device__ __forceinline__ float wave_sum(float v){
  #pragma unroll
  for (int o=32;o;o>>=1) v += __shfl_xor(v,o);
  return v;
}
__device__ __forceinline__ float wave_max(float v){
  #pragma unroll
  for (int o=32;o;o>>=1) v = fmaxf(v,__shfl_xor(v,o));
  return v;
}
__device__ __forceinline__ float sigmoidf_(float x){ return 1.0f/(1.0f+expf(-x)); }
__device__ __forceinline__ u16 f2b(float f){
  unsigned u = __float_as_uint(f);
  unsigned r = (u + 0x7fffu + ((u>>16)&1u)) >> 16;
  return (u16)r;
}
__device__ __forceinline__ float b2f(u16 h){ return __uint_as_float(((unsigned)h)<<16); }

// ---------------------------------------------------------------------------
// bf16 MFMA GEMM: C[m,n] = sum_k A[m,k]*W[n,k] (+bias[n]).
// A rows at stride lda, W row-major [N,K]. 128x128 tile, BK=64, 256 thr =
// 4 waves (2x2 of 64x64), each wave 4x4 MFMA tiles. M mult of 128.
// ksplit: blockIdx.y = mtile*ksplit+ksp; fp32 partial at C + ksp*M*N.
// bf16 epilogue LDS-staged (HBM write-amp fix); fp32 epilogue direct.
// ---------------------------------------------------------------------------
struct MArgs {
  const u16* A[4]; const u16* W[4]; const float* bias[4]; void* C[4];
  int M, N, K, lda, ksplit, out_bf16;
};

__global__ __launch_bounds__(256, 2) void mfma_gemm(MArgs g) {
  const int z = blockIdx.z;
  const u16* __restrict__ A = g.A[z];
  const u16* __restrict__ W = g.W[z];
  const float* __restrict__ bias = g.bias[z];
  const int N = g.N, K = g.K, lda = g.lda;
  const int mtile = blockIdx.y / g.ksplit;
  const int ksp   = blockIdx.y % g.ksplit;
  const int m0 = mtile*128, n0 = blockIdx.x*128;
  const int kc = K / g.ksplit;
  const int kbeg = ksp*kc, kend = kbeg+kc;

  // row stride 88 bf16 = 176 B: 16B-aligned, 2-way-max bank aliasing on b128
  __shared__ __align__(16) u16 sh[2*128*88];   // 45056 B
  u16* As = sh;
  u16* Bs = sh + 128*88;

  const int tid = threadIdx.x;
  const int wave = tid>>6, lane = tid&63;
  const int wm = (wave>>1)*64, wn = (wave&1)*64;
  const int m16 = lane&15, quad = lane>>4;

  f32x4 acc[4][4];
  #pragma unroll
  for (int i=0;i<4;i++)
    #pragma unroll
    for (int j=0;j<4;j++) acc[i][j] = (f32x4){0.f,0.f,0.f,0.f};

  for (int kt = kbeg; kt < kend; kt += 64) {
    uint4 av[4], wv[4];
    #pragma unroll
    for (int it=0; it<4; it++){
      int idx = tid + it*256;
      int r = idx>>3, c = idx&7;
      av[it] = *(const uint4*)(A + (size_t)(m0+r)*lda + kt + c*8);
      wv[it] = *(const uint4*)(W + (size_t)(n0+r)*K + kt + c*8);
    }
    __syncthreads();
    #pragma unroll
    for (int it=0; it<4; it++){
      int idx = tid + it*256;
      int r = idx>>3, c = idx&7;
      *(uint4*)&As[r*88 + c*8] = av[it];
      *(uint4*)&Bs[r*88 + c*8] = wv[it];
    }
    __syncthreads();
    #pragma unroll
    for (int ks=0; ks<2; ks++){
      bf16x8 af[4], bfr[4];
      #pragma unroll
      for (int i=0;i<4;i++) af[i] = *(const bf16x8*)&As[(wm + i*16 + m16)*88 + ks*32 + quad*8];
      #pragma unroll
      for (int j=0;j<4;j++) bfr[j] = *(const bf16x8*)&Bs[(wn + j*16 + m16)*88 + ks*32 + quad*8];
      #pragma unroll
      for (int i=0;i<4;i++)
        #pragma unroll
        for (int j=0;j<4;j++)
          acc[i][j] = __builtin_amdgcn_mfma_f32_16x16x32_bf16(af[i], bfr[j], acc[i][j], 0, 0, 0);
    }
  }

  if (g.out_bf16) {
    // stage bf16 tile (bias added) in LDS, then write coalesced uint4 rows
    u16* C = (u16*)g.C[z];
    __syncthreads();
    #pragma unroll
    for (int i=0;i<4;i++){
      #pragma unroll
      for (int j=0;j<4;j++){
        int cc = wn + j*16 + m16;
        float bv = bias ? bias[n0 + cc] : 0.0f;
        #pragma unroll
        for (int r=0;r<4;r++)
          sh[(wm + i*16 + quad*4 + r)*128 + cc] = f2b(acc[i][j][r] + bv);
      }
    }
    __syncthreads();
    #pragma unroll
    for (int k=0;k<8;k++){
      int idx = tid + k*256;
      int row = idx>>4, c = idx&15;
      *(uint4*)(C + (size_t)(m0+row)*N + n0 + c*8) = *(const uint4*)&sh[row*128 + c*8];
    }
  } else {
    // fp32: direct stores (outputs are L2-resident, re-read immediately)
    float* C = (float*)g.C[z] + (size_t)ksp*g.M*N;
    #pragma unroll
    for (int i=0;i<4;i++){
      int mb = m0 + wm + i*16 + quad*4;
      #pragma unroll
      for (int j=0;j<4;j++){
        int n = n0 + wn + j*16 + m16;
        float bv = bias ? bias[n] : 0.0f;
        #pragma unroll
        for (int r=0;r<4;r++)
          C[(size_t)(mb+r)*N + n] = acc[i][j][r] + bv;
      }
    }
  }
}

// ---------------------------------------------------------------------------
// Batched fp32 -> bf16 conversions (job per blockIdx.y)
// ---------------------------------------------------------------------------
struct F2BJobs { const float* s[8]; u16* d[8]; int n4; };

__global__ void f2b_multi(F2BJobs J){
  const float* __restrict__ src = J.s[blockIdx.y];
  u16* __restrict__ dst = J.d[blockIdx.y];
  int i = blockIdx.x*blockDim.x + threadIdx.x;
  if (i >= J.n4) return;
  float4 v = *(const float4*)(src + (size_t)i*4);
  ushort4 o; o.x=f2b(v.x); o.y=f2b(v.y); o.z=f2b(v.z); o.w=f2b(v.w);
  *(ushort4*)(dst + (size_t)i*4) = o;
}

// [S,B,H] fp32 -> [(b*S+s),H] bf16 (proj-GEMM A layout); blockIdx.y picks job
__global__ void remap2_kernel(const float* __restrict__ srcA, u16* __restrict__ dstA,
                              const float* __restrict__ srcB, u16* __restrict__ dstB){
  const float* __restrict__ src = blockIdx.y ? srcB : srcA;
  u16* __restrict__ dst = blockIdx.y ? dstB : dstA;
  int i = blockIdx.x*blockDim.x + threadIdx.x;     // over S*B*H/4
  if (i >= (S_LEN*BATCH*HDIM)/4) return;
  int elem = i*4;
  int s = elem >> 18;            // /(B*H)
  int b = (elem >> 9) & 511;
  int h = elem & 511;
  float4 v = *(const float4*)(src + (size_t)s*BATCH*HDIM + (size_t)b*HDIM + h);
  ushort4 o; o.x=f2b(v.x); o.y=f2b(v.y); o.z=f2b(v.z); o.w=f2b(v.w);
  *(ushort4*)(dst + ((size_t)b*S_LEN + s)*HDIM + h) = o;
}

// ---------------------------------------------------------------------------
// init: states + decoder inputs (bf16 activations, fp32 c), mask
// ---------------------------------------------------------------------------
__global__ void init_kernel(const float* __restrict__ h0, const float* __restrict__ c0,
                            const float* __restrict__ h0a, const float* __restrict__ c0a,
                            const float* __restrict__ dec, const unsigned char* __restrict__ vmask,
                            u16* __restrict__ h_bf, float* __restrict__ c_ws,
                            u16* __restrict__ x_bf, u16* __restrict__ xa_bf,
                            int* __restrict__ mask){
  for (int i = blockIdx.x*blockDim.x + threadIdx.x; i < BH; i += gridDim.x*blockDim.x) {
    h_bf[i]=f2b(h0[i]); h_bf[BH+i]=f2b(h0a[i]);
    c_ws[i]=c0[i];      c_ws[BH+i]=c0a[i];
    u16 d = f2b(dec[i]);
    x_bf[i]=d; xa_bf[i]=d;
    if (i < BS) mask[i] = vmask[i] ? 1 : 0;
  }
}

__global__ __launch_bounds__(64) void mask_fix_kernel(int* __restrict__ mask){
  int b = blockIdx.x, lane = threadIdx.x;
  int mv = (lane < S_LEN) ? mask[b*S_LEN+lane] : 1;
  unsigned long long bal = __ballot(mv != 0);
  if ((bal & MASK50) == MASK50 && lane == 49) mask[b*S_LEN+49] = 0;
}

// ---------------------------------------------------------------------------
// LSTM gate nonlinearity. g_ws: [0]=x*Wih^T [1]=h*Whh^T (main), [2],[3] aoi.
// Writes h as bf16 (GEMM operand), c as fp32.
// ---------------------------------------------------------------------------
__global__ void gates_kernel(const float* __restrict__ g_ws,
                             const float* __restrict__ b_ih, const float* __restrict__ b_hh,
                             const float* __restrict__ b_ih_a, const float* __restrict__ b_hh_a,
                             u16* __restrict__ h_bf, float* __restrict__ c_ws){
  int i = blockIdx.x*blockDim.x + threadIdx.x;          // over 2*BH
  if (i >= 2*BH) return;
  int z = i / BH, r = i % BH;
  int b = r >> 9, j = r & 511;
  const float* gA = g_ws + (size_t)(2*z+0)*BATCH*H4 + (size_t)b*H4;
  const float* gB = g_ws + (size_t)(2*z+1)*BATCH*H4 + (size_t)b*H4;
  const float* bi = z ? b_ih_a : b_ih;
  const float* bh = z ? b_hh_a : b_hh;
  float gi = gA[j]      + gB[j]      + bi[j]      + bh[j];
  float gf = gA[512+j]  + gB[512+j]  + bi[512+j]  + bh[512+j];
  float gg = gA[1024+j] + gB[1024+j] + bi[1024+j] + bh[1024+j];
  float go = gA[1536+j] + gB[1536+j] + bi[1536+j] + bh[1536+j];
  float cp = c_ws[i];
  float c2 = sigmoidf_(gf)*cp + sigmoidf_(gi)*tanhf(gg);
  float h2 = sigmoidf_(go)*tanhf(c2);
  c_ws[i] = c2; h_bf[i] = f2b(h2);
}

// ---------------------------------------------------------------------------
// Glimpse attention: e-slice (50 KB, contiguous) staged in LDS once; logits,
// softmax, and weighted sum all read LDS. q from KSPQ fp32 partials + bq.
// ---------------------------------------------------------------------------
__global__ __launch_bounds__(512) void glimpse_kernel(
    const float* __restrict__ qpart,
    const float* __restrict__ bq_g, const float* __restrict__ bq_ga,
    const u16* __restrict__ e_g, const u16* __restrict__ e_ga,
    const float* __restrict__ v_g, const float* __restrict__ v_ga,
    const int* __restrict__ mask, u16* __restrict__ gl_ws){
  int z = blockIdx.y, b = blockIdx.x, tid = threadIdx.x;
  const u16* e = (z ? e_ga : e_g) + (size_t)b*S_LEN*HDIM;
  const float* v  = z ? v_ga : v_g;
  const float* bq = z ? bq_ga : bq_g;
  const float* qp = qpart + (size_t)z*KSPQ*BH + (size_t)b*HDIM;
  __shared__ __align__(16) u16 e_lds[S_LEN*HDIM];   // 51200 B
  __shared__ float lg_sh[64], p_sh[64];
  int w = tid>>6, lane = tid&63;
  int h0 = lane*8;

  // cooperative contiguous load of the e-slice (3200 uint4)
  {
    const uint4* s4 = (const uint4*)e;
    uint4* d4 = (uint4*)e_lds;
    #pragma unroll
    for (int i=0;i<7;i++) d4[tid + i*512] = s4[tid + i*512];
    if (tid < 3200 - 7*512) d4[tid + 7*512] = s4[tid + 7*512];
  }

  float qreg[8], vreg[8];
  #pragma unroll
  for (int ii=0; ii<8; ii++){
    int h = h0+ii;
    float q = bq[h];
    #pragma unroll
    for (int p=0;p<KSPQ;p++) q += qp[(size_t)p*BH + h];
    qreg[ii]=q; vreg[ii]=v[h];
  }
  __syncthreads();

  for (int s = w; s < S_LEN; s += 8) {
    const u16* pe = &e_lds[s*HDIM + h0];
    float acc = 0.0f;
    #pragma unroll
    for (int ii=0; ii<8; ii++) acc += vreg[ii]*tanhf(qreg[ii] + b2f(pe[ii]));
    acc = wave_sum(acc);
    if (lane==0) lg_sh[s] = mask[b*S_LEN+s] ? -INFINITY : acc;
  }
  __syncthreads();
  if (tid < 64) {
    float val = (tid < S_LEN) ? lg_sh[tid] : -INFINITY;
    float mx = wave_max(val);
    float ex = (tid < S_LEN) ? expf(val - mx) : 0.0f;
    float sm = wave_sum(ex);
    if (tid < S_LEN) p_sh[tid] = ex / sm;
  }
  __syncthreads();
  float acc = 0.0f;
  for (int s=0;s<S_LEN;s++) acc += p_sh[s]*b2f(e_lds[s*HDIM + tid]);
  gl_ws[(size_t)z*BH + (size_t)b*HDIM + tid] = f2b(acc);
}

// ---------------------------------------------------------------------------
// Fused pointer + combine + gather (R6-proven inner code). One block per b,
// 512 thr = 8 waves; waves 0-3 z=0, waves 4-7 z=1. q2 from qp-GEMM split-K
// partials + bq_p. Output clamps -inf -> -1e30.
// ---------------------------------------------------------------------------
__global__ __launch_bounds__(512) void pointer_combine_kernel(
    const float* __restrict__ q2part,
    const float* __restrict__ bq_p, const float* __restrict__ bq_pa,
    const u16* __restrict__ e_p, const u16* __restrict__ e_pa,
    const float* __restrict__ v_p, const float* __restrict__ v_pa,
    int* __restrict__ mask,
    const u16* __restrict__ emb_bf, const u16* __restrict__ ench_bf,
    u16* __restrict__ x_bf, u16* __restrict__ xa_bf,
    float* __restrict__ out, int t){
  int b = blockIdx.x, tid = threadIdx.x;
  int w = tid>>6, lane = tid&63;
  int z = w>>2, wz = w&3;
  __shared__ float sh_q2[2][HDIM];
  __shared__ float sh_lp[2][64];
  __shared__ int idx_sh;

  // q2[zz][h] = bq + sum of split-K partials (thread tid <-> h)
  #pragma unroll
  for (int zz=0; zz<2; zz++){
    const float* qp = q2part + (size_t)zz*KSPQ*BH + (size_t)b*HDIM;
    float a2 = (zz ? bq_pa : bq_p)[tid];
    #pragma unroll
    for (int p=0;p<KSPQ;p++) a2 += qp[(size_t)p*BH + tid];
    sh_q2[zz][tid] = a2;
  }
  __syncthreads();

  const u16* ep = (z ? e_pa : e_p) + (size_t)b*S_LEN*HDIM;
  const float* vp = z ? v_pa : v_p;
  int h0 = lane*8;
  float q2r[8], vpr[8];
  #pragma unroll
  for (int ii=0; ii<8; ii++){ q2r[ii]=sh_q2[z][h0+ii]; vpr[ii]=vp[h0+ii]; }
  for (int s = wz; s < S_LEN; s += 4) {
    uint4 ev = *(const uint4*)(ep + (size_t)s*HDIM + h0);
    const u16* pe = (const u16*)&ev;
    float acc = 0.0f;
    #pragma unroll
    for (int ii=0; ii<8; ii++) acc += vpr[ii]*tanhf(q2r[ii] + b2f(pe[ii]));
    acc = wave_sum(acc);
    if (lane==0) sh_lp[z][s] = mask[b*S_LEN+s] ? -INFINITY : 10.0f*tanhf(acc);
  }
  __syncthreads();

  if (tid < 64) {
    float a  = (lane < S_LEN) ? sh_lp[0][lane] : -INFINITY;
    float ca = (lane < S_LEN) ? sh_lp[1][lane] : -INFINITY;
    float m1 = wave_max(a);
    float l1 = logf(wave_sum((lane < S_LEN) ? expf(a - m1) : 0.0f));
    float m2 = wave_max(ca);
    float l2 = logf(wave_sum((lane < S_LEN) ? expf(ca - m2) : 0.0f));
    float logp = (a - m1 - l1) + 0.1f * (ca - m2 - l2);
    if (lane < S_LEN) out[(size_t)b*(S_LEN*S_LEN) + t*S_LEN + lane] = fmaxf(logp, -1e30f);
    float vv = (lane < S_LEN) ? logp : -INFINITY;
    int bi = lane;
    #pragma unroll
    for (int o=32;o;o>>=1) {
      float ov = __shfl_xor(vv, o); int oi = __shfl_xor(bi, o);
      if (ov > vv || (ov == vv && oi < bi)) { vv = ov; bi = oi; }
    }
    int idx = bi;
    if (lane == 0) { out[(size_t)BATCH*S_LEN*S_LEN + b*S_LEN + t] = (float)idx; idx_sh = idx; }
    int mv = 1;
    if (lane < S_LEN) { mv = mask[b*S_LEN+lane]; if (lane==idx) mv = 1; mask[b*S_LEN+lane] = mv; }
    unsigned long long bal = __ballot(mv != 0);
    if ((bal & MASK50) == MASK50 && lane == 49) mask[b*S_LEN+49] = 0;
  }
  __syncthreads();

  int idx = idx_sh;
  x_bf[(size_t)b*HDIM + tid]  = emb_bf[((size_t)idx*BATCH + b)*HDIM + tid];
  xa_bf[(size_t)b*HDIM + tid] = ench_bf[((size_t)idx*BATCH + b)*HDIM + tid];
}

// ---------------------------------------------------------------------------
extern "C" void kernel_launch(void* const* d_in, const int* in_sizes, int n_in,
                              void* d_out, int out_size, void* d_ws, size_t ws_size,
                              hipStream_t stream) {
  (void)in_sizes; (void)n_in; (void)out_size; (void)ws_size;
  const float* dec    = (const float*)d_in[0];
  const float* emb    = (const float*)d_in[1];
  const float* h0     = (const float*)d_in[2];
  const float* c0     = (const float*)d_in[3];
  const float* ctx    = (const float*)d_in[4];
  const float* ench   = (const float*)d_in[5];
  const float* dia    = (const float*)d_in[6];
  const float* h0a    = (const float*)d_in[7];
  const float* c0a    = (const float*)d_in[8];
  const unsigned char* vmask = (const unsigned char*)d_in[9];
  const float* W_ih   = (const float*)d_in[10];
  const float* W_hh   = (const float*)d_in[11];
  const float* b_ih   = (const float*)d_in[12];
  const float* b_hh   = (const float*)d_in[13];
  const float* W_ih_a = (const float*)d_in[14];
  const float* W_hh_a = (const float*)d_in[15];
  const float* b_ih_a = (const float*)d_in[16];
  const float* b_hh_a = (const float*)d_in[17];
  const float* Wq_p  = (const float*)d_in[18];
  const float* bq_p  = (const float*)d_in[19];
  const float* Wr_p  = (const float*)d_in[20];
  const float* br_p  = (const float*)d_in[21];
  const float* v_p   = (const float*)d_in[22];
  const float* Wq_pa = (const float*)d_in[23];
  const float* bq_pa = (const float*)d_in[24];
  const float* Wr_pa = (const float*)d_in[25];
  const float* br_pa = (const float*)d_in[26];
  const float* v_pa  = (const float*)d_in[27];
  const float* Wq_g  = (const float*)d_in[28];
  const float* bq_g  = (const float*)d_in[29];
  const float* Wr_g  = (const float*)d_in[30];
  const float* br_g  = (const float*)d_in[31];
  const float* v_g   = (const float*)d_in[32];
  const float* Wq_ga = (const float*)d_in[33];
  const float* bq_ga = (const float*)d_in[34];
  const float* Wr_ga = (const float*)d_in[35];
  const float* br_ga = (const float*)d_in[36];
  const float* v_ga  = (const float*)d_in[37];

  char* base = (char*)d_ws;
  size_t off = 0;
  auto carve = [&](size_t bytes)->char*{ char* p = base + off; off += (bytes + 255) & ~(size_t)255; return p; };

  const size_t E_BYTES = (size_t)BS*HDIM*2;      // 26,214,400
  u16* e_g   = (u16*)carve(E_BYTES);
  u16* e_p   = (u16*)carve(E_BYTES);
  u16* e_ga  = (u16*)carve(E_BYTES);
  u16* e_pa  = (u16*)carve(E_BYTES);
  char* scratch = carve(2*E_BYTES);              // A_ctx/A_dia, later emb/ench bf16
  u16* A_ctx  = (u16*)scratch;
  u16* A_dia  = (u16*)(scratch + E_BYTES);
  u16* emb_bf  = A_ctx;                          // aliases (prologue-ordered)
  u16* ench_bf = A_dia;
  u16* Wih_bf  = (u16*)carve((size_t)H4*HDIM*2);
  u16* Whh_bf  = (u16*)carve((size_t)H4*HDIM*2);
  u16* Wiha_bf = (u16*)carve((size_t)H4*HDIM*2);
  u16* Whha_bf = (u16*)carve((size_t)H4*HDIM*2);
  u16* Wqg_bf  = (u16*)carve((size_t)BH*2);      // 512x512
  u16* Wqga_bf = (u16*)carve((size_t)BH*2);
  u16* Wqp_bf  = (u16*)carve((size_t)BH*2);
  u16* Wqpa_bf = (u16*)carve((size_t)BH*2);
  u16* Wrg_bf  = (u16*)carve((size_t)BH*2);
  u16* Wrp_bf  = (u16*)carve((size_t)BH*2);
  u16* Wrga_bf = (u16*)carve((size_t)BH*2);
  u16* Wrpa_bf = (u16*)carve((size_t)BH*2);
  u16* x_bf    = (u16*)carve((size_t)BH*2);
  u16* xa_bf   = (u16*)carve((size_t)BH*2);
  u16* h_bf    = (u16*)carve((size_t)2*BH*2);    // [2][B][H]
  float* c_ws  = (float*)carve((size_t)2*BH*4);
  float* g_ws  = (float*)carve((size_t)4*BATCH*H4*4);
  u16* gl      = (u16*)carve((size_t)2*BH*2);
  float* q_ws  = (float*)carve((size_t)2*KSPQ*BH*4);
  float* q2_ws = (float*)carve((size_t)2*KSPQ*BH*4);
  int*   mask  = (int*)carve((size_t)BS*4);
  float* out   = (float*)d_out;

  init_kernel<<<1024, 256, 0, stream>>>(h0, c0, h0a, c0a, dec, vmask,
                                        h_bf, c_ws, x_bf, xa_bf, mask);
  mask_fix_kernel<<<BATCH, 64, 0, stream>>>(mask);

  // --- prologue conversions (batched) ---
  const int RB = ((S_LEN*BATCH*HDIM/4)+255)/256;
  remap2_kernel<<<dim3(RB,2), 256, 0, stream>>>(ctx, A_ctx, dia, A_dia);

  const int NW4 = H4*HDIM/4, NWQ = BH/4;
  F2BJobs jw{};   // 4 LSTM weight matrices [2048x512]
  jw.s[0]=W_ih; jw.d[0]=Wih_bf;  jw.s[1]=W_hh; jw.d[1]=Whh_bf;
  jw.s[2]=W_ih_a; jw.d[2]=Wiha_bf; jw.s[3]=W_hh_a; jw.d[3]=Whha_bf;
  jw.n4 = NW4;
  f2b_multi<<<dim3((NW4+255)/256,4), 256, 0, stream>>>(jw);

  F2BJobs jq{};   // 8 attention weight matrices [512x512]
  jq.s[0]=Wq_g;  jq.d[0]=Wqg_bf;  jq.s[1]=Wq_ga; jq.d[1]=Wqga_bf;
  jq.s[2]=Wq_p;  jq.d[2]=Wqp_bf;  jq.s[3]=Wq_pa; jq.d[3]=Wqpa_bf;
  jq.s[4]=Wr_g;  jq.d[4]=Wrg_bf;  jq.s[5]=Wr_p;  jq.d[5]=Wrp_bf;
  jq.s[6]=Wr_ga; jq.d[6]=Wrga_bf; jq.s[7]=Wr_pa; jq.d[7]=Wrpa_bf;
  jq.n4 = NWQ;
  f2b_multi<<<dim3((NWQ+255)/256,8), 256, 0, stream>>>(jq);

  // Hoisted context projections -> e (bf16, [B,S,H] row = b*S+s)
  MArgs pa{};
  pa.A[0]=A_ctx; pa.A[1]=A_ctx; pa.A[2]=A_dia; pa.A[3]=A_dia;
  pa.W[0]=Wrg_bf; pa.W[1]=Wrp_bf; pa.W[2]=Wrga_bf; pa.W[3]=Wrpa_bf;
  pa.bias[0]=br_g; pa.bias[1]=br_p; pa.bias[2]=br_ga; pa.bias[3]=br_pa;
  pa.C[0]=e_g; pa.C[1]=e_p; pa.C[2]=e_ga; pa.C[3]=e_pa;
  pa.M=BS; pa.N=HDIM; pa.K=HDIM; pa.lda=HDIM; pa.ksplit=1; pa.out_bf16=1;
  mfma_gemm<<<dim3(4,200,4), 256, 0, stream>>>(pa);

  // emb/ench bf16 copies into the (now dead) A_ctx/A_dia space
  const int NE = S_LEN*BATCH*HDIM/4;
  F2BJobs je{};
  je.s[0]=emb; je.d[0]=emb_bf; je.s[1]=ench; je.d[1]=ench_bf;
  je.n4 = NE;
  f2b_multi<<<dim3((NE+255)/256,2), 256, 0, stream>>>(je);

  // --- per-step GEMM arg sets ---
  MArgs la{};
  la.A[0]=x_bf; la.A[1]=h_bf; la.A[2]=xa_bf; la.A[3]=h_bf+BH;
  la.W[0]=Wih_bf; la.W[1]=Whh_bf; la.W[2]=Wiha_bf; la.W[3]=Whha_bf;
  la.bias[0]=la.bias[1]=la.bias[2]=la.bias[3]=nullptr;
  la.C[0]=g_ws; la.C[1]=g_ws+(size_t)BATCH*H4; la.C[2]=g_ws+2*(size_t)BATCH*H4; la.C[3]=g_ws+3*(size_t)BATCH*H4;
  la.M=BATCH; la.N=H4; la.K=HDIM; la.lda=HDIM; la.ksplit=1; la.out_bf16=0;

  MArgs qg{};
  qg.A[0]=h_bf; qg.A[1]=h_bf+BH;
  qg.W[0]=Wqg_bf; qg.W[1]=Wqga_bf;
  qg.bias[0]=qg.bias[1]=qg.bias[2]=qg.bias[3]=nullptr;
  qg.C[0]=q_ws; qg.C[1]=q_ws+(size_t)KSPQ*BH;
  qg.M=BATCH; qg.N=HDIM; qg.K=HDIM; qg.lda=HDIM; qg.ksplit=KSPQ; qg.out_bf16=0;

  MArgs qp{};
  qp.A[0]=gl; qp.A[1]=gl+BH;
  qp.W[0]=Wqp_bf; qp.W[1]=Wqpa_bf;
  qp.bias[0]=qp.bias[1]=qp.bias[2]=qp.bias[3]=nullptr;
  qp.C[0]=q2_ws; qp.C[1]=q2_ws+(size_t)KSPQ*BH;
  qp.M=BATCH; qp.N=HDIM; qp.K=HDIM; qp.lda=HDIM; qp.ksplit=KSPQ; qp.out_bf16=0;

  for (int t = 0; t < S_LEN; ++t) {
    mfma_gemm<<<dim3(16,4,4), 256, 0, stream>>>(la);
    gates_kernel<<<(2*BH+255)/256, 256, 0, stream>>>(g_ws, b_ih, b_hh, b_ih_a, b_hh_a, h_bf, c_ws);
    mfma_gemm<<<dim3(4,4*KSPQ,2), 256, 0, stream>>>(qg);
    glimpse_kernel<<<dim3(BATCH,2), 512, 0, stream>>>(q_ws, bq_g, bq_ga, e_g, e_ga, v_g, v_ga, mask, gl);
    mfma_gemm<<<dim3(4,4*KSPQ,2), 256, 0, stream>>>(qp);
    pointer_combine_kernel<<<BATCH, 512, 0, stream>>>(
        q2_ws, bq_p, bq_pa, e_p, e_pa, v_p, v_pa,
        mask, emb_bf, ench_bf, x_bf, xa_bf, out, t);
  }
}

// Round 7
// 5421.083 us; speedup vs baseline: 1.1742x; 1.1742x over previous
//
#include <hip/hip_runtime.h>
#include <math.h>

// ---------------------------------------------------------------------------
// Pointer-network decoder, 50 sequential greedy-decode steps.
// R10 = R8 (best measured artifact, 6178 us) + ONE change: fast transcendental
// math in the hot per-step kernels. tanhf (libm, ~20-30 VALU ops w/ precise
// division) -> tanh_fast = 1 - 2*rcp(exp(2x)+1) (~5 ops, v_exp+v_rcp,
// exact +-1 saturation). sigmoid -> rcp(1+exp(-x)). ~52M tanh/step in
// glimpse+pointer logits is the dominant VALU work in the two biggest
// per-step kernels. Everything else byte-identical to R8.
// ---------------------------------------------------------------------------

#define S_LEN 50
#define BATCH 512
#define HDIM  512
#define H4    2048
#define BH    (BATCH*HDIM)          // 262144
#define BS    (BATCH*S_LEN)         // 25600
#define KSPQ  4                     // split-K for the small q GEMMs
#define MASK50 0x0003FFFFFFFFFFFFULL

typedef unsigned short u16;
typedef __attribute__((ext_vector_type(8))) short bf16x8;
typedef __attribute__((ext_vector_type(4))) float f32x4;

__device__ __forceinline__ float wave_sum(float v){
  #pragma unroll
  for (int o=32;o;o>>=1) v += __shfl_xor(v,o);
  return v;
}
__device__ __forceinline__ float wave_max(float v){
  #pragma unroll
  for (int o=32;o;o>>=1) v = fmaxf(v,__shfl_xor(v,o));
  return v;
}
// fast tanh: 1 - 2/(e^{2x}+1). v_exp_f32 + v_rcp_f32; saturates exactly to
// +-1 (x>>0: exp=inf -> rcp=0 -> 1; x<<0: exp=0 -> rcp(1)=1 -> -1).
__device__ __forceinline__ float tanh_fast(float x){
  float t = __expf(2.0f*x);
  return 1.0f - 2.0f*__builtin_amdgcn_rcpf(t + 1.0f);
}
__device__ __forceinline__ float sigmoid_fast(float x){
  return __builtin_amdgcn_rcpf(1.0f + __expf(-x));
}
__device__ __forceinline__ u16 f2b(float f){
  unsigned u = __float_as_uint(f);
  unsigned r = (u + 0x7fffu + ((u>>16)&1u)) >> 16;
  return (u16)r;
}
__device__ __forceinline__ float b2f(u16 h){ return __uint_as_float(((unsigned)h)<<16); }

// ---------------------------------------------------------------------------
// bf16 MFMA GEMM: C[m,n] = sum_k A[m,k]*W[n,k] (+bias[n]).
// A rows at stride lda, W row-major [N,K]. 128x128 tile, BK=64, 256 thr =
// 4 waves (2x2 of 64x64), each wave 4x4 MFMA tiles. M mult of 128.
// ksplit: blockIdx.y = mtile*ksplit+ksp; fp32 partial at C + ksp*M*N.
// Both epilogues LDS-staged -> fully coalesced wide stores (write-amp fix).
// ---------------------------------------------------------------------------
struct MArgs {
  const u16* A[4]; const u16* W[4]; const float* bias[4]; void* C[4];
  int M, N, K, lda, ksplit, out_bf16;
};

__global__ __launch_bounds__(256, 2) void mfma_gemm(MArgs g) {
  const int z = blockIdx.z;
  const u16* __restrict__ A = g.A[z];
  const u16* __restrict__ W = g.W[z];
  const float* __restrict__ bias = g.bias[z];
  const int N = g.N, K = g.K, lda = g.lda;
  const int mtile = blockIdx.y / g.ksplit;
  const int ksp   = blockIdx.y % g.ksplit;
  const int m0 = mtile*128, n0 = blockIdx.x*128;
  const int kc = K / g.ksplit;
  const int kbeg = ksp*kc, kend = kbeg+kc;

  // row stride 88 bf16 = 176 B: 16B-aligned, 2-way-max bank aliasing on b128
  __shared__ __align__(16) u16 sh[2*128*88];   // 45056 B
  u16* As = sh;
  u16* Bs = sh + 128*88;

  const int tid = threadIdx.x;
  const int wave = tid>>6, lane = tid&63;
  const int wm = (wave>>1)*64, wn = (wave&1)*64;
  const int m16 = lane&15, quad = lane>>4;

  f32x4 acc[4][4];
  #pragma unroll
  for (int i=0;i<4;i++)
    #pragma unroll
    for (int j=0;j<4;j++) acc[i][j] = (f32x4){0.f,0.f,0.f,0.f};

  for (int kt = kbeg; kt < kend; kt += 64) {
    uint4 av[4], wv[4];
    #pragma unroll
    for (int it=0; it<4; it++){
      int idx = tid + it*256;
      int r = idx>>3, c = idx&7;
      av[it] = *(const uint4*)(A + (size_t)(m0+r)*lda + kt + c*8);
      wv[it] = *(const uint4*)(W + (size_t)(n0+r)*K + kt + c*8);
    }
    __syncthreads();
    #pragma unroll
    for (int it=0; it<4; it++){
      int idx = tid + it*256;
      int r = idx>>3, c = idx&7;
      *(uint4*)&As[r*88 + c*8] = av[it];
      *(uint4*)&Bs[r*88 + c*8] = wv[it];
    }
    __syncthreads();
    #pragma unroll
    for (int ks=0; ks<2; ks++){
      bf16x8 af[4], bfr[4];
      #pragma unroll
      for (int i=0;i<4;i++) af[i] = *(const bf16x8*)&As[(wm + i*16 + m16)*88 + ks*32 + quad*8];
      #pragma unroll
      for (int j=0;j<4;j++) bfr[j] = *(const bf16x8*)&Bs[(wn + j*16 + m16)*88 + ks*32 + quad*8];
      #pragma unroll
      for (int i=0;i<4;i++)
        #pragma unroll
        for (int j=0;j<4;j++)
          acc[i][j] = __builtin_amdgcn_mfma_f32_16x16x32_bf16(af[i], bfr[j], acc[i][j], 0, 0, 0);
    }
  }

  if (g.out_bf16) {
    // stage bf16 tile (bias added) in LDS, then write coalesced uint4 rows
    u16* C = (u16*)g.C[z];
    __syncthreads();
    #pragma unroll
    for (int i=0;i<4;i++){
      #pragma unroll
      for (int j=0;j<4;j++){
        int cc = wn + j*16 + m16;
        float bv = bias ? bias[n0 + cc] : 0.0f;
        #pragma unroll
        for (int r=0;r<4;r++)
          sh[(wm + i*16 + quad*4 + r)*128 + cc] = f2b(acc[i][j][r] + bv);
      }
    }
    __syncthreads();
    #pragma unroll
    for (int k=0;k<8;k++){
      int idx = tid + k*256;
      int row = idx>>4, c = idx&15;
      *(uint4*)(C + (size_t)(m0+row)*N + n0 + c*8) = *(const uint4*)&sh[row*128 + c*8];
    }
  } else {
    // fp32: stage 64 rows at a time (64x128 fp32 = 32 KB fits in the 44 KB
    // LDS block), store coalesced float4. Wave-uniform guards; straight-line.
    float* C = (float*)g.C[z] + (size_t)ksp*g.M*N;
    float* shf = (float*)sh;
    // pass 0: rows 0..63 (waves 0,1 own them: wm==0)
    __syncthreads();
    if (wm == 0){
      #pragma unroll
      for (int i=0;i<4;i++){
        int mb = i*16 + quad*4;
        #pragma unroll
        for (int j=0;j<4;j++){
          int cc = wn + j*16 + m16;
          float bv = bias ? bias[n0 + cc] : 0.0f;
          #pragma unroll
          for (int r=0;r<4;r++) shf[(mb+r)*128 + cc] = acc[i][j][r] + bv;
        }
      }
    }
    __syncthreads();
    #pragma unroll
    for (int k=0;k<8;k++){
      int idx = tid + k*256;
      int row = idx>>5, c = idx&31;
      *(float4*)(C + (size_t)(m0 + row)*N + n0 + c*4) = *(const float4*)&shf[row*128 + c*4];
    }
    // pass 1: rows 64..127 (waves 2,3: wm==64)
    __syncthreads();
    if (wm == 64){
      #pragma unroll
      for (int i=0;i<4;i++){
        int mb = i*16 + quad*4;
        #pragma unroll
        for (int j=0;j<4;j++){
          int cc = wn + j*16 + m16;
          float bv = bias ? bias[n0 + cc] : 0.0f;
          #pragma unroll
          for (int r=0;r<4;r++) shf[(mb+r)*128 + cc] = acc[i][j][r] + bv;
        }
      }
    }
    __syncthreads();
    #pragma unroll
    for (int k=0;k<8;k++){
      int idx = tid + k*256;
      int row = idx>>5, c = idx&31;
      *(float4*)(C + (size_t)(m0 + 64 + row)*N + n0 + c*4) = *(const float4*)&shf[row*128 + c*4];
    }
  }
}

// ---------------------------------------------------------------------------
// Batched fp32 -> bf16 conversions (job per blockIdx.y)
// ---------------------------------------------------------------------------
struct F2BJobs { const float* s[8]; u16* d[8]; int n4; };

__global__ void f2b_multi(F2BJobs J){
  const float* __restrict__ src = J.s[blockIdx.y];
  u16* __restrict__ dst = J.d[blockIdx.y];
  int i = blockIdx.x*blockDim.x + threadIdx.x;
  if (i >= J.n4) return;
  float4 v = *(const float4*)(src + (size_t)i*4);
  ushort4 o; o.x=f2b(v.x); o.y=f2b(v.y); o.z=f2b(v.z); o.w=f2b(v.w);
  *(ushort4*)(dst + (size_t)i*4) = o;
}

// [S,B,H] fp32 -> [(b*S+s),H] bf16 (proj-GEMM A layout); blockIdx.y picks job
__global__ void remap2_kernel(const float* __restrict__ srcA, u16* __restrict__ dstA,
                              const float* __restrict__ srcB, u16* __restrict__ dstB){
  const float* __restrict__ src = blockIdx.y ? srcB : srcA;
  u16* __restrict__ dst = blockIdx.y ? dstB : dstA;
  int i = blockIdx.x*blockDim.x + threadIdx.x;     // over S*B*H/4
  if (i >= (S_LEN*BATCH*HDIM)/4) return;
  int elem = i*4;
  int s = elem >> 18;            // /(B*H)
  int b = (elem >> 9) & 511;
  int h = elem & 511;
  float4 v = *(const float4*)(src + (size_t)s*BATCH*HDIM + (size_t)b*HDIM + h);
  ushort4 o; o.x=f2b(v.x); o.y=f2b(v.y); o.z=f2b(v.z); o.w=f2b(v.w);
  *(ushort4*)(dst + ((size_t)b*S_LEN + s)*HDIM + h) = o;
}

// ---------------------------------------------------------------------------
// init: states + decoder inputs (bf16 activations, fp32 c), mask
// ---------------------------------------------------------------------------
__global__ void init_kernel(const float* __restrict__ h0, const float* __restrict__ c0,
                            const float* __restrict__ h0a, const float* __restrict__ c0a,
                            const float* __restrict__ dec, const unsigned char* __restrict__ vmask,
                            u16* __restrict__ h_bf, float* __restrict__ c_ws,
                            u16* __restrict__ x_bf, u16* __restrict__ xa_bf,
                            int* __restrict__ mask){
  for (int i = blockIdx.x*blockDim.x + threadIdx.x; i < BH; i += gridDim.x*blockDim.x) {
    h_bf[i]=f2b(h0[i]); h_bf[BH+i]=f2b(h0a[i]);
    c_ws[i]=c0[i];      c_ws[BH+i]=c0a[i];
    u16 d = f2b(dec[i]);
    x_bf[i]=d; xa_bf[i]=d;
    if (i < BS) mask[i] = vmask[i] ? 1 : 0;
  }
}

__global__ __launch_bounds__(64) void mask_fix_kernel(int* __restrict__ mask){
  int b = blockIdx.x, lane = threadIdx.x;
  int mv = (lane < S_LEN) ? mask[b*S_LEN+lane] : 1;
  unsigned long long bal = __ballot(mv != 0);
  if ((bal & MASK50) == MASK50 && lane == 49) mask[b*S_LEN+49] = 0;
}

// ---------------------------------------------------------------------------
// LSTM gate nonlinearity. g_ws: [0]=x*Wih^T [1]=h*Whh^T (main), [2],[3] aoi.
// Writes h as bf16 (GEMM operand), c as fp32.
// ---------------------------------------------------------------------------
__global__ void gates_kernel(const float* __restrict__ g_ws,
                             const float* __restrict__ b_ih, const float* __restrict__ b_hh,
                             const float* __restrict__ b_ih_a, const float* __restrict__ b_hh_a,
                             u16* __restrict__ h_bf, float* __restrict__ c_ws){
  int i = blockIdx.x*blockDim.x + threadIdx.x;          // over 2*BH
  if (i >= 2*BH) return;
  int z = i / BH, r = i % BH;
  int b = r >> 9, j = r & 511;
  const float* gA = g_ws + (size_t)(2*z+0)*BATCH*H4 + (size_t)b*H4;
  const float* gB = g_ws + (size_t)(2*z+1)*BATCH*H4 + (size_t)b*H4;
  const float* bi = z ? b_ih_a : b_ih;
  const float* bh = z ? b_hh_a : b_hh;
  float gi = gA[j]      + gB[j]      + bi[j]      + bh[j];
  float gf = gA[512+j]  + gB[512+j]  + bi[512+j]  + bh[512+j];
  float gg = gA[1024+j] + gB[1024+j] + bi[1024+j] + bh[1024+j];
  float go = gA[1536+j] + gB[1536+j] + bi[1536+j] + bh[1536+j];
  float cp = c_ws[i];
  float c2 = sigmoid_fast(gf)*cp + sigmoid_fast(gi)*tanh_fast(gg);
  float h2 = sigmoid_fast(go)*tanh_fast(c2);
  c_ws[i] = c2; h_bf[i] = f2b(h2);
}

// ---------------------------------------------------------------------------
// Glimpse attention on bf16 e [B,S,H]: logits+mask+softmax+weighted sum.
// q = sum of KSPQ fp32 partials + bq, held in registers (8 contig h per lane).
// ---------------------------------------------------------------------------
__global__ __launch_bounds__(512) void glimpse_kernel(
    const float* __restrict__ qpart,
    const float* __restrict__ bq_g, const float* __restrict__ bq_ga,
    const u16* __restrict__ e_g, const u16* __restrict__ e_ga,
    const float* __restrict__ v_g, const float* __restrict__ v_ga,
    const int* __restrict__ mask, u16* __restrict__ gl_ws){
  int z = blockIdx.y, b = blockIdx.x, tid = threadIdx.x;
  const u16* e = (z ? e_ga : e_g) + (size_t)b*S_LEN*HDIM;
  const float* v  = z ? v_ga : v_g;
  const float* bq = z ? bq_ga : bq_g;
  const float* qp = qpart + (size_t)z*KSPQ*BH + (size_t)b*HDIM;
  __shared__ float lg_sh[64], p_sh[64];
  int w = tid>>6, lane = tid&63;
  int h0 = lane*8;
  float qreg[8], vreg[8];
  #pragma unroll
  for (int ii=0; ii<8; ii++){
    int h = h0+ii;
    float q = bq[h];
    #pragma unroll
    for (int p=0;p<KSPQ;p++) q += qp[(size_t)p*BH + h];
    qreg[ii]=q; vreg[ii]=v[h];
  }
  for (int s = w; s < S_LEN; s += 8) {
    uint4 ev = *(const uint4*)(e + (size_t)s*HDIM + h0);
    const u16* pe = (const u16*)&ev;
    float acc = 0.0f;
    #pragma unroll
    for (int ii=0; ii<8; ii++) acc += vreg[ii]*tanh_fast(qreg[ii] + b2f(pe[ii]));
    acc = wave_sum(acc);
    if (lane==0) lg_sh[s] = mask[b*S_LEN+s] ? -INFINITY : acc;
  }
  __syncthreads();
  if (tid < 64) {
    float val = (tid < S_LEN) ? lg_sh[tid] : -INFINITY;
    float mx = wave_max(val);
    float ex = (tid < S_LEN) ? expf(val - mx) : 0.0f;
    float sm = wave_sum(ex);
    if (tid < S_LEN) p_sh[tid] = ex / sm;
  }
  __syncthreads();
  float acc = 0.0f;
  for (int s=0;s<S_LEN;s++) acc += p_sh[s]*b2f(e[(size_t)s*HDIM + tid]);
  gl_ws[(size_t)z*BH + (size_t)b*HDIM + tid] = f2b(acc);
}

// ---------------------------------------------------------------------------
// Pointer attention: lp[s] = mask ? -inf : 10*tanh(sum_h v*tanh(q+e))
// ---------------------------------------------------------------------------
__global__ __launch_bounds__(512) void pointer_kernel(
    const float* __restrict__ qpart,
    const float* __restrict__ bq_p, const float* __restrict__ bq_pa,
    const u16* __restrict__ e_p, const u16* __restrict__ e_pa,
    const float* __restrict__ v_p, const float* __restrict__ v_pa,
    const int* __restrict__ mask, float* __restrict__ lp_ws){
  int z = blockIdx.y, b = blockIdx.x, tid = threadIdx.x;
  const u16* e = (z ? e_pa : e_p) + (size_t)b*S_LEN*HDIM;
  const float* v  = z ? v_pa : v_p;
  const float* bq = z ? bq_pa : bq_p;
  const float* qp = qpart + (size_t)z*KSPQ*BH + (size_t)b*HDIM;
  int w = tid>>6, lane = tid&63;
  int h0 = lane*8;
  float qreg[8], vreg[8];
  #pragma unroll
  for (int ii=0; ii<8; ii++){
    int h = h0+ii;
    float q = bq[h];
    #pragma unroll
    for (int p=0;p<KSPQ;p++) q += qp[(size_t)p*BH + h];
    qreg[ii]=q; vreg[ii]=v[h];
  }
  for (int s = w; s < S_LEN; s += 8) {
    uint4 ev = *(const uint4*)(e + (size_t)s*HDIM + h0);
    const u16* pe = (const u16*)&ev;
    float acc = 0.0f;
    #pragma unroll
    for (int ii=0; ii<8; ii++) acc += vreg[ii]*tanh_fast(qreg[ii] + b2f(pe[ii]));
    acc = wave_sum(acc);
    if (lane==0) lp_ws[(size_t)z*BS + b*S_LEN + s] = mask[b*S_LEN+s] ? -INFINITY : 10.0f*tanh_fast(acc);
  }
}

// ---------------------------------------------------------------------------
// Combine: log_softmax(lp)+0.1*log_softmax(lpa), argmax, gather, mask update.
// Output write clamps -inf -> -1e30 (harness absmax NaNs on inf-inf).
// ---------------------------------------------------------------------------
__global__ __launch_bounds__(64) void combine_kernel(
    const float* __restrict__ lp_ws, float* __restrict__ out, int t,
    const u16* __restrict__ emb_bf, const u16* __restrict__ ench_bf,
    u16* __restrict__ x_bf, u16* __restrict__ xa_bf, int* __restrict__ mask){
  int b = blockIdx.x, lane = threadIdx.x;
  float a  = (lane < S_LEN) ? lp_ws[b*S_LEN + lane]       : -INFINITY;
  float ca = (lane < S_LEN) ? lp_ws[BS + b*S_LEN + lane]  : -INFINITY;
  float m1 = wave_max(a);
  float l1 = logf(wave_sum((lane < S_LEN) ? expf(a - m1) : 0.0f));
  float m2 = wave_max(ca);
  float l2 = logf(wave_sum((lane < S_LEN) ? expf(ca - m2) : 0.0f));
  float logp = (a - m1 - l1) + 0.1f * (ca - m2 - l2);
  if (lane < S_LEN) out[(size_t)b*(S_LEN*S_LEN) + t*S_LEN + lane] = fmaxf(logp, -1e30f);
  float v = (lane < S_LEN) ? logp : -INFINITY;
  int bi = lane;
  #pragma unroll
  for (int o=32;o;o>>=1) {
    float ov = __shfl_xor(v, o); int oi = __shfl_xor(bi, o);
    if (ov > v || (ov == v && oi < bi)) { v = ov; bi = oi; }
  }
  int idx = bi;
  if (lane == 0) out[(size_t)BATCH*S_LEN*S_LEN + b*S_LEN + t] = (float)idx;
  const u16* esrc = emb_bf  + ((size_t)idx*BATCH + b)*HDIM;
  const u16* asrc = ench_bf + ((size_t)idx*BATCH + b)*HDIM;
  u16* xdst = x_bf  + (size_t)b*HDIM;
  u16* adst = xa_bf + (size_t)b*HDIM;
  for (int e0 = lane; e0 < HDIM; e0 += 64) { xdst[e0] = esrc[e0]; adst[e0] = asrc[e0]; }
  int mv = 1;
  if (lane < S_LEN) { mv = mask[b*S_LEN+lane]; if (lane==idx) mv = 1; mask[b*S_LEN+lane] = mv; }
  unsigned long long bal = __ballot(mv != 0);
  if ((bal & MASK50) == MASK50 && lane == 49) mask[b*S_LEN+49] = 0;
}

// ---------------------------------------------------------------------------
extern "C" void kernel_launch(void* const* d_in, const int* in_sizes, int n_in,
                              void* d_out, int out_size, void* d_ws, size_t ws_size,
                              hipStream_t stream) {
  (void)in_sizes; (void)n_in; (void)out_size; (void)ws_size;
  const float* dec    = (const float*)d_in[0];
  const float* emb    = (const float*)d_in[1];
  const float* h0     = (const float*)d_in[2];
  const float* c0     = (const float*)d_in[3];
  const float* ctx    = (const float*)d_in[4];
  const float* ench   = (const float*)d_in[5];
  const float* dia    = (const float*)d_in[6];
  const float* h0a    = (const float*)d_in[7];
  const float* c0a    = (const float*)d_in[8];
  const unsigned char* vmask = (const unsigned char*)d_in[9];
  const float* W_ih   = (const float*)d_in[10];
  const float* W_hh   = (const float*)d_in[11];
  const float* b_ih   = (const float*)d_in[12];
  const float* b_hh   = (const float*)d_in[13];
  const float* W_ih_a = (const float*)d_in[14];
  const float* W_hh_a = (const float*)d_in[15];
  const float* b_ih_a = (const float*)d_in[16];
  const float* b_hh_a = (const float*)d_in[17];
  const float* Wq_p  = (const float*)d_in[18];
  const float* bq_p  = (const float*)d_in[19];
  const float* Wr_p  = (const float*)d_in[20];
  const float* br_p  = (const float*)d_in[21];
  const float* v_p   = (const float*)d_in[22];
  const float* Wq_pa = (const float*)d_in[23];
  const float* bq_pa = (const float*)d_in[24];
  const float* Wr_pa = (const float*)d_in[25];
  const float* br_pa = (const float*)d_in[26];
  const float* v_pa  = (const float*)d_in[27];
  const float* Wq_g  = (const float*)d_in[28];
  const float* bq_g  = (const float*)d_in[29];
  const float* Wr_g  = (const float*)d_in[30];
  const float* br_g  = (const float*)d_in[31];
  const float* v_g   = (const float*)d_in[32];
  const float* Wq_ga = (const float*)d_in[33];
  const float* bq_ga = (const float*)d_in[34];
  const float* Wr_ga = (const float*)d_in[35];
  const float* br_ga = (const float*)d_in[36];
  const float* v_ga  = (const float*)d_in[37];

  char* base = (char*)d_ws;
  size_t off = 0;
  auto carve = [&](size_t bytes)->char*{ char* p = base + off; off += (bytes + 255) & ~(size_t)255; return p; };

  const size_t E_BYTES = (size_t)BS*HDIM*2;      // 26,214,400
  u16* e_g   = (u16*)carve(E_BYTES);
  u16* e_p   = (u16*)carve(E_BYTES);
  u16* e_ga  = (u16*)carve(E_BYTES);
  u16* e_pa  = (u16*)carve(E_BYTES);
  char* scratch = carve(2*E_BYTES);              // A_ctx/A_dia, later emb/ench bf16
  u16* A_ctx  = (u16*)scratch;
  u16* A_dia  = (u16*)(scratch + E_BYTES);
  u16* emb_bf  = A_ctx;                          // aliases (prologue-ordered)
  u16* ench_bf = A_dia;
  u16* Wih_bf  = (u16*)carve((size_t)H4*HDIM*2);
  u16* Whh_bf  = (u16*)carve((size_t)H4*HDIM*2);
  u16* Wiha_bf = (u16*)carve((size_t)H4*HDIM*2);
  u16* Whha_bf = (u16*)carve((size_t)H4*HDIM*2);
  u16* Wqg_bf  = (u16*)carve((size_t)BH*2);      // 512x512
  u16* Wqga_bf = (u16*)carve((size_t)BH*2);
  u16* Wqp_bf  = (u16*)carve((size_t)BH*2);
  u16* Wqpa_bf = (u16*)carve((size_t)BH*2);
  u16* Wrg_bf  = (u16*)carve((size_t)BH*2);
  u16* Wrp_bf  = (u16*)carve((size_t)BH*2);
  u16* Wrga_bf = (u16*)carve((size_t)BH*2);
  u16* Wrpa_bf = (u16*)carve((size_t)BH*2);
  u16* x_bf    = (u16*)carve((size_t)BH*2);
  u16* xa_bf   = (u16*)carve((size_t)BH*2);
  u16* h_bf    = (u16*)carve((size_t)2*BH*2);    // [2][B][H]
  float* c_ws  = (float*)carve((size_t)2*BH*4);
  float* g_ws  = (float*)carve((size_t)4*BATCH*H4*4);
  u16* gl      = (u16*)carve((size_t)2*BH*2);
  float* q_ws  = (float*)carve((size_t)2*KSPQ*BH*4);
  float* q2_ws = (float*)carve((size_t)2*KSPQ*BH*4);
  float* lp_ws = (float*)carve((size_t)2*BS*4);
  int*   mask  = (int*)carve((size_t)BS*4);
  float* out   = (float*)d_out;

  init_kernel<<<1024, 256, 0, stream>>>(h0, c0, h0a, c0a, dec, vmask,
                                        h_bf, c_ws, x_bf, xa_bf, mask);
  mask_fix_kernel<<<BATCH, 64, 0, stream>>>(mask);

  // --- prologue conversions (batched) ---
  const int RB = ((S_LEN*BATCH*HDIM/4)+255)/256;
  remap2_kernel<<<dim3(RB,2), 256, 0, stream>>>(ctx, A_ctx, dia, A_dia);

  const int NW4 = H4*HDIM/4, NWQ = BH/4;
  F2BJobs jw{};   // 4 LSTM weight matrices [2048x512]
  jw.s[0]=W_ih; jw.d[0]=Wih_bf;  jw.s[1]=W_hh; jw.d[1]=Whh_bf;
  jw.s[2]=W_ih_a; jw.d[2]=Wiha_bf; jw.s[3]=W_hh_a; jw.d[3]=Whha_bf;
  jw.n4 = NW4;
  f2b_multi<<<dim3((NW4+255)/256,4), 256, 0, stream>>>(jw);

  F2BJobs jq{};   // 8 attention weight matrices [512x512]
  jq.s[0]=Wq_g;  jq.d[0]=Wqg_bf;  jq.s[1]=Wq_ga; jq.d[1]=Wqga_bf;
  jq.s[2]=Wq_p;  jq.d[2]=Wqp_bf;  jq.s[3]=Wq_pa; jq.d[3]=Wqpa_bf;
  jq.s[4]=Wr_g;  jq.d[4]=Wrg_bf;  jq.s[5]=Wr_p;  jq.d[5]=Wrp_bf;
  jq.s[6]=Wr_ga; jq.d[6]=Wrga_bf; jq.s[7]=Wr_pa; jq.d[7]=Wrpa_bf;
  jq.n4 = NWQ;
  f2b_multi<<<dim3((NWQ+255)/256,8), 256, 0, stream>>>(jq);

  // Hoisted context projections -> e (bf16, [B,S,H] row = b*S+s)
  MArgs pa{};
  pa.A[0]=A_ctx; pa.A[1]=A_ctx; pa.A[2]=A_dia; pa.A[3]=A_dia;
  pa.W[0]=Wrg_bf; pa.W[1]=Wrp_bf; pa.W[2]=Wrga_bf; pa.W[3]=Wrpa_bf;
  pa.bias[0]=br_g; pa.bias[1]=br_p; pa.bias[2]=br_ga; pa.bias[3]=br_pa;
  pa.C[0]=e_g; pa.C[1]=e_p; pa.C[2]=e_ga; pa.C[3]=e_pa;
  pa.M=BS; pa.N=HDIM; pa.K=HDIM; pa.lda=HDIM; pa.ksplit=1; pa.out_bf16=1;
  mfma_gemm<<<dim3(4,200,4), 256, 0, stream>>>(pa);

  // emb/ench bf16 copies into the (now dead) A_ctx/A_dia space
  const int NE = S_LEN*BATCH*HDIM/4;
  F2BJobs je{};
  je.s[0]=emb; je.d[0]=emb_bf; je.s[1]=ench; je.d[1]=ench_bf;
  je.n4 = NE;
  f2b_multi<<<dim3((NE+255)/256,2), 256, 0, stream>>>(je);

  // --- per-step GEMM arg sets ---
  MArgs la{};
  la.A[0]=x_bf; la.A[1]=h_bf; la.A[2]=xa_bf; la.A[3]=h_bf+BH;
  la.W[0]=Wih_bf; la.W[1]=Whh_bf; la.W[2]=Wiha_bf; la.W[3]=Whha_bf;
  la.bias[0]=la.bias[1]=la.bias[2]=la.bias[3]=nullptr;
  la.C[0]=g_ws; la.C[1]=g_ws+(size_t)BATCH*H4; la.C[2]=g_ws+2*(size_t)BATCH*H4; la.C[3]=g_ws+3*(size_t)BATCH*H4;
  la.M=BATCH; la.N=H4; la.K=HDIM; la.lda=HDIM; la.ksplit=1; la.out_bf16=0;

  MArgs qg{};
  qg.A[0]=h_bf; qg.A[1]=h_bf+BH;
  qg.W[0]=Wqg_bf; qg.W[1]=Wqga_bf;
  qg.bias[0]=qg.bias[1]=qg.bias[2]=qg.bias[3]=nullptr;
  qg.C[0]=q_ws; qg.C[1]=q_ws+(size_t)KSPQ*BH;
  qg.M=BATCH; qg.N=HDIM; qg.K=HDIM; qg.lda=HDIM; qg.ksplit=KSPQ; qg.out_bf16=0;

  MArgs qp{};
  qp.A[0]=gl; qp.A[1]=gl+BH;
  qp.W[0]=Wqp_bf; qp.W[1]=Wqpa_bf;
  qp.bias[0]=qp.bias[1]=qp.bias[2]=qp.bias[3]=nullptr;
  qp.C[0]=q2_ws; qp.C[1]=q2_ws+(size_t)KSPQ*BH;
  qp.M=BATCH; qp.N=HDIM; qp.K=HDIM; qp.lda=HDIM; qp.ksplit=KSPQ; qp.out_bf16=0;

  for (int t = 0; t < S_LEN; ++t) {
    mfma_gemm<<<dim3(16,4,4), 256, 0, stream>>>(la);
    gates_kernel<<<(2*BH+255)/256, 256, 0, stream>>>(g_ws, b_ih, b_hh, b_ih_a, b_hh_a, h_bf, c_ws);
    mfma_gemm<<<dim3(4,4*KSPQ,2), 256, 0, stream>>>(qg);
    glimpse_kernel<<<dim3(BATCH,2), 512, 0, stream>>>(q_ws, bq_g, bq_ga, e_g, e_ga, v_g, v_ga, mask, gl);
    mfma_gemm<<<dim3(4,4*KSPQ,2), 256, 0, stream>>>(qp);
    pointer_kernel<<<dim3(BATCH,2), 512, 0, stream>>>(q2_ws, bq_p, bq_pa, e_p, e_pa, v_p, v_pa, mask, lp_ws);
    combine_kernel<<<BATCH, 64, 0, stream>>>(lp_ws, out, t, emb_bf, ench_bf, x_bf, xa_bf, mask);
  }
}

// Round 8
// 5321.339 us; speedup vs baseline: 1.1962x; 1.0187x over previous
//
#include <hip/hip_runtime.h>
#include <math.h>

// ---------------------------------------------------------------------------
// Pointer-network decoder, 50 sequential greedy-decode steps.
// R11 = R10 (5421 us; fast-math win) + ONE change: pointer+combine fused
// (R6/R9-proven inner code) -> 6 dispatches/step, lp_ws roundtrip gone,
// combine reads logits from LDS. Everything else byte-identical to R10.
// ---------------------------------------------------------------------------

#define S_LEN 50
#define BATCH 512
#define HDIM  512
#define H4    2048
#define BH    (BATCH*HDIM)          // 262144
#define BS    (BATCH*S_LEN)         // 25600
#define KSPQ  4                     // split-K for the small q GEMMs
#define MASK50 0x0003FFFFFFFFFFFFULL

typedef unsigned short u16;
typedef __attribute__((ext_vector_type(8))) short bf16x8;
typedef __attribute__((ext_vector_type(4))) float f32x4;

__device__ __forceinline__ float wave_sum(float v){
  #pragma unroll
  for (int o=32;o;o>>=1) v += __shfl_xor(v,o);
  return v;
}
__device__ __forceinline__ float wave_max(float v){
  #pragma unroll
  for (int o=32;o;o>>=1) v = fmaxf(v,__shfl_xor(v,o));
  return v;
}
// fast tanh: 1 - 2/(e^{2x}+1). v_exp_f32 + v_rcp_f32; saturates exactly to
// +-1 (x>>0: exp=inf -> rcp=0 -> 1; x<<0: exp=0 -> rcp(1)=1 -> -1).
__device__ __forceinline__ float tanh_fast(float x){
  float t = __expf(2.0f*x);
  return 1.0f - 2.0f*__builtin_amdgcn_rcpf(t + 1.0f);
}
__device__ __forceinline__ float sigmoid_fast(float x){
  return __builtin_amdgcn_rcpf(1.0f + __expf(-x));
}
__device__ __forceinline__ u16 f2b(float f){
  unsigned u = __float_as_uint(f);
  unsigned r = (u + 0x7fffu + ((u>>16)&1u)) >> 16;
  return (u16)r;
}
__device__ __forceinline__ float b2f(u16 h){ return __uint_as_float(((unsigned)h)<<16); }

// ---------------------------------------------------------------------------
// bf16 MFMA GEMM: C[m,n] = sum_k A[m,k]*W[n,k] (+bias[n]).
// A rows at stride lda, W row-major [N,K]. 128x128 tile, BK=64, 256 thr =
// 4 waves (2x2 of 64x64), each wave 4x4 MFMA tiles. M mult of 128.
// ksplit: blockIdx.y = mtile*ksplit+ksp; fp32 partial at C + ksp*M*N.
// Both epilogues LDS-staged -> fully coalesced wide stores (write-amp fix).
// ---------------------------------------------------------------------------
struct MArgs {
  const u16* A[4]; const u16* W[4]; const float* bias[4]; void* C[4];
  int M, N, K, lda, ksplit, out_bf16;
};

__global__ __launch_bounds__(256, 2) void mfma_gemm(MArgs g) {
  const int z = blockIdx.z;
  const u16* __restrict__ A = g.A[z];
  const u16* __restrict__ W = g.W[z];
  const float* __restrict__ bias = g.bias[z];
  const int N = g.N, K = g.K, lda = g.lda;
  const int mtile = blockIdx.y / g.ksplit;
  const int ksp   = blockIdx.y % g.ksplit;
  const int m0 = mtile*128, n0 = blockIdx.x*128;
  const int kc = K / g.ksplit;
  const int kbeg = ksp*kc, kend = kbeg+kc;

  // row stride 88 bf16 = 176 B: 16B-aligned, 2-way-max bank aliasing on b128
  __shared__ __align__(16) u16 sh[2*128*88];   // 45056 B
  u16* As = sh;
  u16* Bs = sh + 128*88;

  const int tid = threadIdx.x;
  const int wave = tid>>6, lane = tid&63;
  const int wm = (wave>>1)*64, wn = (wave&1)*64;
  const int m16 = lane&15, quad = lane>>4;

  f32x4 acc[4][4];
  #pragma unroll
  for (int i=0;i<4;i++)
    #pragma unroll
    for (int j=0;j<4;j++) acc[i][j] = (f32x4){0.f,0.f,0.f,0.f};

  for (int kt = kbeg; kt < kend; kt += 64) {
    uint4 av[4], wv[4];
    #pragma unroll
    for (int it=0; it<4; it++){
      int idx = tid + it*256;
      int r = idx>>3, c = idx&7;
      av[it] = *(const uint4*)(A + (size_t)(m0+r)*lda + kt + c*8);
      wv[it] = *(const uint4*)(W + (size_t)(n0+r)*K + kt + c*8);
    }
    __syncthreads();
    #pragma unroll
    for (int it=0; it<4; it++){
      int idx = tid + it*256;
      int r = idx>>3, c = idx&7;
      *(uint4*)&As[r*88 + c*8] = av[it];
      *(uint4*)&Bs[r*88 + c*8] = wv[it];
    }
    __syncthreads();
    #pragma unroll
    for (int ks=0; ks<2; ks++){
      bf16x8 af[4], bfr[4];
      #pragma unroll
      for (int i=0;i<4;i++) af[i] = *(const bf16x8*)&As[(wm + i*16 + m16)*88 + ks*32 + quad*8];
      #pragma unroll
      for (int j=0;j<4;j++) bfr[j] = *(const bf16x8*)&Bs[(wn + j*16 + m16)*88 + ks*32 + quad*8];
      #pragma unroll
      for (int i=0;i<4;i++)
        #pragma unroll
        for (int j=0;j<4;j++)
          acc[i][j] = __builtin_amdgcn_mfma_f32_16x16x32_bf16(af[i], bfr[j], acc[i][j], 0, 0, 0);
    }
  }

  if (g.out_bf16) {
    // stage bf16 tile (bias added) in LDS, then write coalesced uint4 rows
    u16* C = (u16*)g.C[z];
    __syncthreads();
    #pragma unroll
    for (int i=0;i<4;i++){
      #pragma unroll
      for (int j=0;j<4;j++){
        int cc = wn + j*16 + m16;
        float bv = bias ? bias[n0 + cc] : 0.0f;
        #pragma unroll
        for (int r=0;r<4;r++)
          sh[(wm + i*16 + quad*4 + r)*128 + cc] = f2b(acc[i][j][r] + bv);
      }
    }
    __syncthreads();
    #pragma unroll
    for (int k=0;k<8;k++){
      int idx = tid + k*256;
      int row = idx>>4, c = idx&15;
      *(uint4*)(C + (size_t)(m0+row)*N + n0 + c*8) = *(const uint4*)&sh[row*128 + c*8];
    }
  } else {
    // fp32: stage 64 rows at a time (64x128 fp32 = 32 KB fits in the 44 KB
    // LDS block), store coalesced float4. Wave-uniform guards; straight-line.
    float* C = (float*)g.C[z] + (size_t)ksp*g.M*N;
    float* shf = (float*)sh;
    // pass 0: rows 0..63 (waves 0,1 own them: wm==0)
    __syncthreads();
    if (wm == 0){
      #pragma unroll
      for (int i=0;i<4;i++){
        int mb = i*16 + quad*4;
        #pragma unroll
        for (int j=0;j<4;j++){
          int cc = wn + j*16 + m16;
          float bv = bias ? bias[n0 + cc] : 0.0f;
          #pragma unroll
          for (int r=0;r<4;r++) shf[(mb+r)*128 + cc] = acc[i][j][r] + bv;
        }
      }
    }
    __syncthreads();
    #pragma unroll
    for (int k=0;k<8;k++){
      int idx = tid + k*256;
      int row = idx>>5, c = idx&31;
      *(float4*)(C + (size_t)(m0 + row)*N + n0 + c*4) = *(const float4*)&shf[row*128 + c*4];
    }
    // pass 1: rows 64..127 (waves 2,3: wm==64)
    __syncthreads();
    if (wm == 64){
      #pragma unroll
      for (int i=0;i<4;i++){
        int mb = i*16 + quad*4;
        #pragma unroll
        for (int j=0;j<4;j++){
          int cc = wn + j*16 + m16;
          float bv = bias ? bias[n0 + cc] : 0.0f;
          #pragma unroll
          for (int r=0;r<4;r++) shf[(mb+r)*128 + cc] = acc[i][j][r] + bv;
        }
      }
    }
    __syncthreads();
    #pragma unroll
    for (int k=0;k<8;k++){
      int idx = tid + k*256;
      int row = idx>>5, c = idx&31;
      *(float4*)(C + (size_t)(m0 + 64 + row)*N + n0 + c*4) = *(const float4*)&shf[row*128 + c*4];
    }
  }
}

// ---------------------------------------------------------------------------
// Batched fp32 -> bf16 conversions (job per blockIdx.y)
// ---------------------------------------------------------------------------
struct F2BJobs { const float* s[8]; u16* d[8]; int n4; };

__global__ void f2b_multi(F2BJobs J){
  const float* __restrict__ src = J.s[blockIdx.y];
  u16* __restrict__ dst = J.d[blockIdx.y];
  int i = blockIdx.x*blockDim.x + threadIdx.x;
  if (i >= J.n4) return;
  float4 v = *(const float4*)(src + (size_t)i*4);
  ushort4 o; o.x=f2b(v.x); o.y=f2b(v.y); o.z=f2b(v.z); o.w=f2b(v.w);
  *(ushort4*)(dst + (size_t)i*4) = o;
}

// [S,B,H] fp32 -> [(b*S+s),H] bf16 (proj-GEMM A layout); blockIdx.y picks job
__global__ void remap2_kernel(const float* __restrict__ srcA, u16* __restrict__ dstA,
                              const float* __restrict__ srcB, u16* __restrict__ dstB){
  const float* __restrict__ src = blockIdx.y ? srcB : srcA;
  u16* __restrict__ dst = blockIdx.y ? dstB : dstA;
  int i = blockIdx.x*blockDim.x + threadIdx.x;     // over S*B*H/4
  if (i >= (S_LEN*BATCH*HDIM)/4) return;
  int elem = i*4;
  int s = elem >> 18;            // /(B*H)
  int b = (elem >> 9) & 511;
  int h = elem & 511;
  float4 v = *(const float4*)(src + (size_t)s*BATCH*HDIM + (size_t)b*HDIM + h);
  ushort4 o; o.x=f2b(v.x); o.y=f2b(v.y); o.z=f2b(v.z); o.w=f2b(v.w);
  *(ushort4*)(dst + ((size_t)b*S_LEN + s)*HDIM + h) = o;
}

// ---------------------------------------------------------------------------
// init: states + decoder inputs (bf16 activations, fp32 c), mask
// ---------------------------------------------------------------------------
__global__ void init_kernel(const float* __restrict__ h0, const float* __restrict__ c0,
                            const float* __restrict__ h0a, const float* __restrict__ c0a,
                            const float* __restrict__ dec, const unsigned char* __restrict__ vmask,
                            u16* __restrict__ h_bf, float* __restrict__ c_ws,
                            u16* __restrict__ x_bf, u16* __restrict__ xa_bf,
                            int* __restrict__ mask){
  for (int i = blockIdx.x*blockDim.x + threadIdx.x; i < BH; i += gridDim.x*blockDim.x) {
    h_bf[i]=f2b(h0[i]); h_bf[BH+i]=f2b(h0a[i]);
    c_ws[i]=c0[i];      c_ws[BH+i]=c0a[i];
    u16 d = f2b(dec[i]);
    x_bf[i]=d; xa_bf[i]=d;
    if (i < BS) mask[i] = vmask[i] ? 1 : 0;
  }
}

__global__ __launch_bounds__(64) void mask_fix_kernel(int* __restrict__ mask){
  int b = blockIdx.x, lane = threadIdx.x;
  int mv = (lane < S_LEN) ? mask[b*S_LEN+lane] : 1;
  unsigned long long bal = __ballot(mv != 0);
  if ((bal & MASK50) == MASK50 && lane == 49) mask[b*S_LEN+49] = 0;
}

// ---------------------------------------------------------------------------
// LSTM gate nonlinearity. g_ws: [0]=x*Wih^T [1]=h*Whh^T (main), [2],[3] aoi.
// Writes h as bf16 (GEMM operand), c as fp32.
// ---------------------------------------------------------------------------
__global__ void gates_kernel(const float* __restrict__ g_ws,
                             const float* __restrict__ b_ih, const float* __restrict__ b_hh,
                             const float* __restrict__ b_ih_a, const float* __restrict__ b_hh_a,
                             u16* __restrict__ h_bf, float* __restrict__ c_ws){
  int i = blockIdx.x*blockDim.x + threadIdx.x;          // over 2*BH
  if (i >= 2*BH) return;
  int z = i / BH, r = i % BH;
  int b = r >> 9, j = r & 511;
  const float* gA = g_ws + (size_t)(2*z+0)*BATCH*H4 + (size_t)b*H4;
  const float* gB = g_ws + (size_t)(2*z+1)*BATCH*H4 + (size_t)b*H4;
  const float* bi = z ? b_ih_a : b_ih;
  const float* bh = z ? b_hh_a : b_hh;
  float gi = gA[j]      + gB[j]      + bi[j]      + bh[j];
  float gf = gA[512+j]  + gB[512+j]  + bi[512+j]  + bh[512+j];
  float gg = gA[1024+j] + gB[1024+j] + bi[1024+j] + bh[1024+j];
  float go = gA[1536+j] + gB[1536+j] + bi[1536+j] + bh[1536+j];
  float cp = c_ws[i];
  float c2 = sigmoid_fast(gf)*cp + sigmoid_fast(gi)*tanh_fast(gg);
  float h2 = sigmoid_fast(go)*tanh_fast(c2);
  c_ws[i] = c2; h_bf[i] = f2b(h2);
}

// ---------------------------------------------------------------------------
// Glimpse attention on bf16 e [B,S,H]: logits+mask+softmax+weighted sum.
// q = sum of KSPQ fp32 partials + bq, held in registers (8 contig h per lane).
// ---------------------------------------------------------------------------
__global__ __launch_bounds__(512) void glimpse_kernel(
    const float* __restrict__ qpart,
    const float* __restrict__ bq_g, const float* __restrict__ bq_ga,
    const u16* __restrict__ e_g, const u16* __restrict__ e_ga,
    const float* __restrict__ v_g, const float* __restrict__ v_ga,
    const int* __restrict__ mask, u16* __restrict__ gl_ws){
  int z = blockIdx.y, b = blockIdx.x, tid = threadIdx.x;
  const u16* e = (z ? e_ga : e_g) + (size_t)b*S_LEN*HDIM;
  const float* v  = z ? v_ga : v_g;
  const float* bq = z ? bq_ga : bq_g;
  const float* qp = qpart + (size_t)z*KSPQ*BH + (size_t)b*HDIM;
  __shared__ float lg_sh[64], p_sh[64];
  int w = tid>>6, lane = tid&63;
  int h0 = lane*8;
  float qreg[8], vreg[8];
  #pragma unroll
  for (int ii=0; ii<8; ii++){
    int h = h0+ii;
    float q = bq[h];
    #pragma unroll
    for (int p=0;p<KSPQ;p++) q += qp[(size_t)p*BH + h];
    qreg[ii]=q; vreg[ii]=v[h];
  }
  for (int s = w; s < S_LEN; s += 8) {
    uint4 ev = *(const uint4*)(e + (size_t)s*HDIM + h0);
    const u16* pe = (const u16*)&ev;
    float acc = 0.0f;
    #pragma unroll
    for (int ii=0; ii<8; ii++) acc += vreg[ii]*tanh_fast(qreg[ii] + b2f(pe[ii]));
    acc = wave_sum(acc);
    if (lane==0) lg_sh[s] = mask[b*S_LEN+s] ? -INFINITY : acc;
  }
  __syncthreads();
  if (tid < 64) {
    float val = (tid < S_LEN) ? lg_sh[tid] : -INFINITY;
    float mx = wave_max(val);
    float ex = (tid < S_LEN) ? expf(val - mx) : 0.0f;
    float sm = wave_sum(ex);
    if (tid < S_LEN) p_sh[tid] = ex / sm;
  }
  __syncthreads();
  float acc = 0.0f;
  for (int s=0;s<S_LEN;s++) acc += p_sh[s]*b2f(e[(size_t)s*HDIM + tid]);
  gl_ws[(size_t)z*BH + (size_t)b*HDIM + tid] = f2b(acc);
}

// ---------------------------------------------------------------------------
// Fused pointer + combine + gather (R6/R9-proven inner code). One block per
// b, 512 thr = 8 waves; waves 0-3 z=0, waves 4-7 z=1. q2 from qp-GEMM
// split-K partials + bq_p. Output clamps -inf -> -1e30.
// ---------------------------------------------------------------------------
__global__ __launch_bounds__(512) void pointer_combine_kernel(
    const float* __restrict__ q2part,
    const float* __restrict__ bq_p, const float* __restrict__ bq_pa,
    const u16* __restrict__ e_p, const u16* __restrict__ e_pa,
    const float* __restrict__ v_p, const float* __restrict__ v_pa,
    int* __restrict__ mask,
    const u16* __restrict__ emb_bf, const u16* __restrict__ ench_bf,
    u16* __restrict__ x_bf, u16* __restrict__ xa_bf,
    float* __restrict__ out, int t){
  int b = blockIdx.x, tid = threadIdx.x;
  int w = tid>>6, lane = tid&63;
  int z = w>>2, wz = w&3;
  __shared__ float sh_q2[2][HDIM];
  __shared__ float sh_lp[2][64];
  __shared__ int idx_sh;

  // q2[zz][h] = bq + sum of split-K partials (thread tid <-> h)
  #pragma unroll
  for (int zz=0; zz<2; zz++){
    const float* qp = q2part + (size_t)zz*KSPQ*BH + (size_t)b*HDIM;
    float a2 = (zz ? bq_pa : bq_p)[tid];
    #pragma unroll
    for (int p=0;p<KSPQ;p++) a2 += qp[(size_t)p*BH + tid];
    sh_q2[zz][tid] = a2;
  }
  __syncthreads();

  const u16* ep = (z ? e_pa : e_p) + (size_t)b*S_LEN*HDIM;
  const float* vp = z ? v_pa : v_p;
  int h0 = lane*8;
  float q2r[8], vpr[8];
  #pragma unroll
  for (int ii=0; ii<8; ii++){ q2r[ii]=sh_q2[z][h0+ii]; vpr[ii]=vp[h0+ii]; }
  for (int s = wz; s < S_LEN; s += 4) {
    uint4 ev = *(const uint4*)(ep + (size_t)s*HDIM + h0);
    const u16* pe = (const u16*)&ev;
    float acc = 0.0f;
    #pragma unroll
    for (int ii=0; ii<8; ii++) acc += vpr[ii]*tanh_fast(q2r[ii] + b2f(pe[ii]));
    acc = wave_sum(acc);
    if (lane==0) sh_lp[z][s] = mask[b*S_LEN+s] ? -INFINITY : 10.0f*tanh_fast(acc);
  }
  __syncthreads();

  if (tid < 64) {
    float a  = (lane < S_LEN) ? sh_lp[0][lane] : -INFINITY;
    float ca = (lane < S_LEN) ? sh_lp[1][lane] : -INFINITY;
    float m1 = wave_max(a);
    float l1 = logf(wave_sum((lane < S_LEN) ? expf(a - m1) : 0.0f));
    float m2 = wave_max(ca);
    float l2 = logf(wave_sum((lane < S_LEN) ? expf(ca - m2) : 0.0f));
    float logp = (a - m1 - l1) + 0.1f * (ca - m2 - l2);
    if (lane < S_LEN) out[(size_t)b*(S_LEN*S_LEN) + t*S_LEN + lane] = fmaxf(logp, -1e30f);
    float vv = (lane < S_LEN) ? logp : -INFINITY;
    int bi = lane;
    #pragma unroll
    for (int o=32;o;o>>=1) {
      float ov = __shfl_xor(vv, o); int oi = __shfl_xor(bi, o);
      if (ov > vv || (ov == vv && oi < bi)) { vv = ov; bi = oi; }
    }
    int idx = bi;
    if (lane == 0) { out[(size_t)BATCH*S_LEN*S_LEN + b*S_LEN + t] = (float)idx; idx_sh = idx; }
    int mv = 1;
    if (lane < S_LEN) { mv = mask[b*S_LEN+lane]; if (lane==idx) mv = 1; mask[b*S_LEN+lane] = mv; }
    unsigned long long bal = __ballot(mv != 0);
    if ((bal & MASK50) == MASK50 && lane == 49) mask[b*S_LEN+49] = 0;
  }
  __syncthreads();

  int idx = idx_sh;
  x_bf[(size_t)b*HDIM + tid]  = emb_bf[((size_t)idx*BATCH + b)*HDIM + tid];
  xa_bf[(size_t)b*HDIM + tid] = ench_bf[((size_t)idx*BATCH + b)*HDIM + tid];
}

// ---------------------------------------------------------------------------
extern "C" void kernel_launch(void* const* d_in, const int* in_sizes, int n_in,
                              void* d_out, int out_size, void* d_ws, size_t ws_size,
                              hipStream_t stream) {
  (void)in_sizes; (void)n_in; (void)out_size; (void)ws_size;
  const float* dec    = (const float*)d_in[0];
  const float* emb    = (const float*)d_in[1];
  const float* h0     = (const float*)d_in[2];
  const float* c0     = (const float*)d_in[3];
  const float* ctx    = (const float*)d_in[4];
  const float* ench   = (const float*)d_in[5];
  const float* dia    = (const float*)d_in[6];
  const float* h0a    = (const float*)d_in[7];
  const float* c0a    = (const float*)d_in[8];
  const unsigned char* vmask = (const unsigned char*)d_in[9];
  const float* W_ih   = (const float*)d_in[10];
  const float* W_hh   = (const float*)d_in[11];
  const float* b_ih   = (const float*)d_in[12];
  const float* b_hh   = (const float*)d_in[13];
  const float* W_ih_a = (const float*)d_in[14];
  const float* W_hh_a = (const float*)d_in[15];
  const float* b_ih_a = (const float*)d_in[16];
  const float* b_hh_a = (const float*)d_in[17];
  const float* Wq_p  = (const float*)d_in[18];
  const float* bq_p  = (const float*)d_in[19];
  const float* Wr_p  = (const float*)d_in[20];
  const float* br_p  = (const float*)d_in[21];
  const float* v_p   = (const float*)d_in[22];
  const float* Wq_pa = (const float*)d_in[23];
  const float* bq_pa = (const float*)d_in[24];
  const float* Wr_pa = (const float*)d_in[25];
  const float* br_pa = (const float*)d_in[26];
  const float* v_pa  = (const float*)d_in[27];
  const float* Wq_g  = (const float*)d_in[28];
  const float* bq_g  = (const float*)d_in[29];
  const float* Wr_g  = (const float*)d_in[30];
  const float* br_g  = (const float*)d_in[31];
  const float* v_g   = (const float*)d_in[32];
  const float* Wq_ga = (const float*)d_in[33];
  const float* bq_ga = (const float*)d_in[34];
  const float* Wr_ga = (const float*)d_in[35];
  const float* br_ga = (const float*)d_in[36];
  const float* v_ga  = (const float*)d_in[37];

  char* base = (char*)d_ws;
  size_t off = 0;
  auto carve = [&](size_t bytes)->char*{ char* p = base + off; off += (bytes + 255) & ~(size_t)255; return p; };

  const size_t E_BYTES = (size_t)BS*HDIM*2;      // 26,214,400
  u16* e_g   = (u16*)carve(E_BYTES);
  u16* e_p   = (u16*)carve(E_BYTES);
  u16* e_ga  = (u16*)carve(E_BYTES);
  u16* e_pa  = (u16*)carve(E_BYTES);
  char* scratch = carve(2*E_BYTES);              // A_ctx/A_dia, later emb/ench bf16
  u16* A_ctx  = (u16*)scratch;
  u16* A_dia  = (u16*)(scratch + E_BYTES);
  u16* emb_bf  = A_ctx;                          // aliases (prologue-ordered)
  u16* ench_bf = A_dia;
  u16* Wih_bf  = (u16*)carve((size_t)H4*HDIM*2);
  u16* Whh_bf  = (u16*)carve((size_t)H4*HDIM*2);
  u16* Wiha_bf = (u16*)carve((size_t)H4*HDIM*2);
  u16* Whha_bf = (u16*)carve((size_t)H4*HDIM*2);
  u16* Wqg_bf  = (u16*)carve((size_t)BH*2);      // 512x512
  u16* Wqga_bf = (u16*)carve((size_t)BH*2);
  u16* Wqp_bf  = (u16*)carve((size_t)BH*2);
  u16* Wqpa_bf = (u16*)carve((size_t)BH*2);
  u16* Wrg_bf  = (u16*)carve((size_t)BH*2);
  u16* Wrp_bf  = (u16*)carve((size_t)BH*2);
  u16* Wrga_bf = (u16*)carve((size_t)BH*2);
  u16* Wrpa_bf = (u16*)carve((size_t)BH*2);
  u16* x_bf    = (u16*)carve((size_t)BH*2);
  u16* xa_bf   = (u16*)carve((size_t)BH*2);
  u16* h_bf    = (u16*)carve((size_t)2*BH*2);    // [2][B][H]
  float* c_ws  = (float*)carve((size_t)2*BH*4);
  float* g_ws  = (float*)carve((size_t)4*BATCH*H4*4);
  u16* gl      = (u16*)carve((size_t)2*BH*2);
  float* q_ws  = (float*)carve((size_t)2*KSPQ*BH*4);
  float* q2_ws = (float*)carve((size_t)2*KSPQ*BH*4);
  int*   mask  = (int*)carve((size_t)BS*4);
  float* out   = (float*)d_out;

  init_kernel<<<1024, 256, 0, stream>>>(h0, c0, h0a, c0a, dec, vmask,
                                        h_bf, c_ws, x_bf, xa_bf, mask);
  mask_fix_kernel<<<BATCH, 64, 0, stream>>>(mask);

  // --- prologue conversions (batched) ---
  const int RB = ((S_LEN*BATCH*HDIM/4)+255)/256;
  remap2_kernel<<<dim3(RB,2), 256, 0, stream>>>(ctx, A_ctx, dia, A_dia);

  const int NW4 = H4*HDIM/4, NWQ = BH/4;
  F2BJobs jw{};   // 4 LSTM weight matrices [2048x512]
  jw.s[0]=W_ih; jw.d[0]=Wih_bf;  jw.s[1]=W_hh; jw.d[1]=Whh_bf;
  jw.s[2]=W_ih_a; jw.d[2]=Wiha_bf; jw.s[3]=W_hh_a; jw.d[3]=Whha_bf;
  jw.n4 = NW4;
  f2b_multi<<<dim3((NW4+255)/256,4), 256, 0, stream>>>(jw);

  F2BJobs jq{};   // 8 attention weight matrices [512x512]
  jq.s[0]=Wq_g;  jq.d[0]=Wqg_bf;  jq.s[1]=Wq_ga; jq.d[1]=Wqga_bf;
  jq.s[2]=Wq_p;  jq.d[2]=Wqp_bf;  jq.s[3]=Wq_pa; jq.d[3]=Wqpa_bf;
  jq.s[4]=Wr_g;  jq.d[4]=Wrg_bf;  jq.s[5]=Wr_p;  jq.d[5]=Wrp_bf;
  jq.s[6]=Wr_ga; jq.d[6]=Wrga_bf; jq.s[7]=Wr_pa; jq.d[7]=Wrpa_bf;
  jq.n4 = NWQ;
  f2b_multi<<<dim3((NWQ+255)/256,8), 256, 0, stream>>>(jq);

  // Hoisted context projections -> e (bf16, [B,S,H] row = b*S+s)
  MArgs pa{};
  pa.A[0]=A_ctx; pa.A[1]=A_ctx; pa.A[2]=A_dia; pa.A[3]=A_dia;
  pa.W[0]=Wrg_bf; pa.W[1]=Wrp_bf; pa.W[2]=Wrga_bf; pa.W[3]=Wrpa_bf;
  pa.bias[0]=br_g; pa.bias[1]=br_p; pa.bias[2]=br_ga; pa.bias[3]=br_pa;
  pa.C[0]=e_g; pa.C[1]=e_p; pa.C[2]=e_ga; pa.C[3]=e_pa;
  pa.M=BS; pa.N=HDIM; pa.K=HDIM; pa.lda=HDIM; pa.ksplit=1; pa.out_bf16=1;
  mfma_gemm<<<dim3(4,200,4), 256, 0, stream>>>(pa);

  // emb/ench bf16 copies into the (now dead) A_ctx/A_dia space
  const int NE = S_LEN*BATCH*HDIM/4;
  F2BJobs je{};
  je.s[0]=emb; je.d[0]=emb_bf; je.s[1]=ench; je.d[1]=ench_bf;
  je.n4 = NE;
  f2b_multi<<<dim3((NE+255)/256,2), 256, 0, stream>>>(je);

  // --- per-step GEMM arg sets ---
  MArgs la{};
  la.A[0]=x_bf; la.A[1]=h_bf; la.A[2]=xa_bf; la.A[3]=h_bf+BH;
  la.W[0]=Wih_bf; la.W[1]=Whh_bf; la.W[2]=Wiha_bf; la.W[3]=Whha_bf;
  la.bias[0]=la.bias[1]=la.bias[2]=la.bias[3]=nullptr;
  la.C[0]=g_ws; la.C[1]=g_ws+(size_t)BATCH*H4; la.C[2]=g_ws+2*(size_t)BATCH*H4; la.C[3]=g_ws+3*(size_t)BATCH*H4;
  la.M=BATCH; la.N=H4; la.K=HDIM; la.lda=HDIM; la.ksplit=1; la.out_bf16=0;

  MArgs qg{};
  qg.A[0]=h_bf; qg.A[1]=h_bf+BH;
  qg.W[0]=Wqg_bf; qg.W[1]=Wqga_bf;
  qg.bias[0]=qg.bias[1]=qg.bias[2]=qg.bias[3]=nullptr;
  qg.C[0]=q_ws; qg.C[1]=q_ws+(size_t)KSPQ*BH;
  qg.M=BATCH; qg.N=HDIM; qg.K=HDIM; qg.lda=HDIM; qg.ksplit=KSPQ; qg.out_bf16=0;

  MArgs qp{};
  qp.A[0]=gl; qp.A[1]=gl+BH;
  qp.W[0]=Wqp_bf; qp.W[1]=Wqpa_bf;
  qp.bias[0]=qp.bias[1]=qp.bias[2]=qp.bias[3]=nullptr;
  qp.C[0]=q2_ws; qp.C[1]=q2_ws+(size_t)KSPQ*BH;
  qp.M=BATCH; qp.N=HDIM; qp.K=HDIM; qp.lda=HDIM; qp.ksplit=KSPQ; qp.out_bf16=0;

  for (int t = 0; t < S_LEN; ++t) {
    mfma_gemm<<<dim3(16,4,4), 256, 0, stream>>>(la);
    gates_kernel<<<(2*BH+255)/256, 256, 0, stream>>>(g_ws, b_ih, b_hh, b_ih_a, b_hh_a, h_bf, c_ws);
    mfma_gemm<<<dim3(4,4*KSPQ,2), 256, 0, stream>>>(qg);
    glimpse_kernel<<<dim3(BATCH,2), 512, 0, stream>>>(q_ws, bq_g, bq_ga, e_g, e_ga, v_g, v_ga, mask, gl);
    mfma_gemm<<<dim3(4,4*KSPQ,2), 256, 0, stream>>>(qp);
    pointer_combine_kernel<<<BATCH, 512, 0, stream>>>(
        q2_ws, bq_p, bq_pa, e_p, e_pa, v_p, v_pa,
        mask, emb_bf, ench_bf, x_bf, xa_bf, out, t);
  }
}

// Round 9
// 4904.839 us; speedup vs baseline: 1.2978x; 1.0849x over previous
//
#include <hip/hip_runtime.h>
#include <math.h>

// ---------------------------------------------------------------------------
// Pointer-network decoder, 50 sequential greedy-decode steps.
// R12 = R11 (5321 us) + ONE change: the F-trick, done right this time.
//   F = e_glimpse @ Wq_p^T hoisted to prologue (linearity: q2 = p@(e@Wq^T)).
//   glimpse's 2nd pass reads F instead of e (SAME traffic) and emits q2
//   directly -> qp GEMM dispatch, gl buffer, and 8 MB/step split-K partial
//   traffic all deleted. 5 dispatches/step. R4-vs-R6 showed this variant
//   is the faster one within a family; R11's base is the proven-best.
// ---------------------------------------------------------------------------

#define S_LEN 50
#define BATCH 512
#define HDIM  512
#define H4    2048
#define BH    (BATCH*HDIM)          // 262144
#define BS    (BATCH*S_LEN)         // 25600
#define KSPQ  4                     // split-K for the qg GEMM
#define MASK50 0x0003FFFFFFFFFFFFULL

typedef unsigned short u16;
typedef __attribute__((ext_vector_type(8))) short bf16x8;
typedef __attribute__((ext_vector_type(4))) float f32x4;

__device__ __forceinline__ float wave_sum(float v){
  #pragma unroll
  for (int o=32;o;o>>=1) v += __shfl_xor(v,o);
  return v;
}
__device__ __forceinline__ float wave_max(float v){
  #pragma unroll
  for (int o=32;o;o>>=1) v = fmaxf(v,__shfl_xor(v,o));
  return v;
}
// fast tanh: 1 - 2/(e^{2x}+1). v_exp_f32 + v_rcp_f32; saturates exactly to
// +-1 (x>>0: exp=inf -> rcp=0 -> 1; x<<0: exp=0 -> rcp(1)=1 -> -1).
__device__ __forceinline__ float tanh_fast(float x){
  float t = __expf(2.0f*x);
  return 1.0f - 2.0f*__builtin_amdgcn_rcpf(t + 1.0f);
}
__device__ __forceinline__ float sigmoid_fast(float x){
  return __builtin_amdgcn_rcpf(1.0f + __expf(-x));
}
__device__ __forceinline__ u16 f2b(float f){
  unsigned u = __float_as_uint(f);
  unsigned r = (u + 0x7fffu + ((u>>16)&1u)) >> 16;
  return (u16)r;
}
__device__ __forceinline__ float b2f(u16 h){ return __uint_as_float(((unsigned)h)<<16); }

// ---------------------------------------------------------------------------
// bf16 MFMA GEMM: C[m,n] = sum_k A[m,k]*W[n,k] (+bias[n]).
// A rows at stride lda, W row-major [N,K]. 128x128 tile, BK=64, 256 thr =
// 4 waves (2x2 of 64x64), each wave 4x4 MFMA tiles. M mult of 128.
// ksplit: blockIdx.y = mtile*ksplit+ksp; fp32 partial at C + ksp*M*N.
// Both epilogues LDS-staged -> fully coalesced wide stores (write-amp fix).
// ---------------------------------------------------------------------------
struct MArgs {
  const u16* A[4]; const u16* W[4]; const float* bias[4]; void* C[4];
  int M, N, K, lda, ksplit, out_bf16;
};

__global__ __launch_bounds__(256, 2) void mfma_gemm(MArgs g) {
  const int z = blockIdx.z;
  const u16* __restrict__ A = g.A[z];
  const u16* __restrict__ W = g.W[z];
  const float* __restrict__ bias = g.bias[z];
  const int N = g.N, K = g.K, lda = g.lda;
  const int mtile = blockIdx.y / g.ksplit;
  const int ksp   = blockIdx.y % g.ksplit;
  const int m0 = mtile*128, n0 = blockIdx.x*128;
  const int kc = K / g.ksplit;
  const int kbeg = ksp*kc, kend = kbeg+kc;

  // row stride 88 bf16 = 176 B: 16B-aligned, 2-way-max bank aliasing on b128
  __shared__ __align__(16) u16 sh[2*128*88];   // 45056 B
  u16* As = sh;
  u16* Bs = sh + 128*88;

  const int tid = threadIdx.x;
  const int wave = tid>>6, lane = tid&63;
  const int wm = (wave>>1)*64, wn = (wave&1)*64;
  const int m16 = lane&15, quad = lane>>4;

  f32x4 acc[4][4];
  #pragma unroll
  for (int i=0;i<4;i++)
    #pragma unroll
    for (int j=0;j<4;j++) acc[i][j] = (f32x4){0.f,0.f,0.f,0.f};

  for (int kt = kbeg; kt < kend; kt += 64) {
    uint4 av[4], wv[4];
    #pragma unroll
    for (int it=0; it<4; it++){
      int idx = tid + it*256;
      int r = idx>>3, c = idx&7;
      av[it] = *(const uint4*)(A + (size_t)(m0+r)*lda + kt + c*8);
      wv[it] = *(const uint4*)(W + (size_t)(n0+r)*K + kt + c*8);
    }
    __syncthreads();
    #pragma unroll
    for (int it=0; it<4; it++){
      int idx = tid + it*256;
      int r = idx>>3, c = idx&7;
      *(uint4*)&As[r*88 + c*8] = av[it];
      *(uint4*)&Bs[r*88 + c*8] = wv[it];
    }
    __syncthreads();
    #pragma unroll
    for (int ks=0; ks<2; ks++){
      bf16x8 af[4], bfr[4];
      #pragma unroll
      for (int i=0;i<4;i++) af[i] = *(const bf16x8*)&As[(wm + i*16 + m16)*88 + ks*32 + quad*8];
      #pragma unroll
      for (int j=0;j<4;j++) bfr[j] = *(const bf16x8*)&Bs[(wn + j*16 + m16)*88 + ks*32 + quad*8];
      #pragma unroll
      for (int i=0;i<4;i++)
        #pragma unroll
        for (int j=0;j<4;j++)
          acc[i][j] = __builtin_amdgcn_mfma_f32_16x16x32_bf16(af[i], bfr[j], acc[i][j], 0, 0, 0);
    }
  }

  if (g.out_bf16) {
    // stage bf16 tile (bias added) in LDS, then write coalesced uint4 rows
    u16* C = (u16*)g.C[z];
    __syncthreads();
    #pragma unroll
    for (int i=0;i<4;i++){
      #pragma unroll
      for (int j=0;j<4;j++){
        int cc = wn + j*16 + m16;
        float bv = bias ? bias[n0 + cc] : 0.0f;
        #pragma unroll
        for (int r=0;r<4;r++)
          sh[(wm + i*16 + quad*4 + r)*128 + cc] = f2b(acc[i][j][r] + bv);
      }
    }
    __syncthreads();
    #pragma unroll
    for (int k=0;k<8;k++){
      int idx = tid + k*256;
      int row = idx>>4, c = idx&15;
      *(uint4*)(C + (size_t)(m0+row)*N + n0 + c*8) = *(const uint4*)&sh[row*128 + c*8];
    }
  } else {
    // fp32: stage 64 rows at a time (64x128 fp32 = 32 KB fits in the 44 KB
    // LDS block), store coalesced float4. Wave-uniform guards; straight-line.
    float* C = (float*)g.C[z] + (size_t)ksp*g.M*N;
    float* shf = (float*)sh;
    // pass 0: rows 0..63 (waves 0,1 own them: wm==0)
    __syncthreads();
    if (wm == 0){
      #pragma unroll
      for (int i=0;i<4;i++){
        int mb = i*16 + quad*4;
        #pragma unroll
        for (int j=0;j<4;j++){
          int cc = wn + j*16 + m16;
          float bv = bias ? bias[n0 + cc] : 0.0f;
          #pragma unroll
          for (int r=0;r<4;r++) shf[(mb+r)*128 + cc] = acc[i][j][r] + bv;
        }
      }
    }
    __syncthreads();
    #pragma unroll
    for (int k=0;k<8;k++){
      int idx = tid + k*256;
      int row = idx>>5, c = idx&31;
      *(float4*)(C + (size_t)(m0 + row)*N + n0 + c*4) = *(const float4*)&shf[row*128 + c*4];
    }
    // pass 1: rows 64..127 (waves 2,3: wm==64)
    __syncthreads();
    if (wm == 64){
      #pragma unroll
      for (int i=0;i<4;i++){
        int mb = i*16 + quad*4;
        #pragma unroll
        for (int j=0;j<4;j++){
          int cc = wn + j*16 + m16;
          float bv = bias ? bias[n0 + cc] : 0.0f;
          #pragma unroll
          for (int r=0;r<4;r++) shf[(mb+r)*128 + cc] = acc[i][j][r] + bv;
        }
      }
    }
    __syncthreads();
    #pragma unroll
    for (int k=0;k<8;k++){
      int idx = tid + k*256;
      int row = idx>>5, c = idx&31;
      *(float4*)(C + (size_t)(m0 + 64 + row)*N + n0 + c*4) = *(const float4*)&shf[row*128 + c*4];
    }
  }
}

// ---------------------------------------------------------------------------
// Batched fp32 -> bf16 conversions (job per blockIdx.y)
// ---------------------------------------------------------------------------
struct F2BJobs { const float* s[8]; u16* d[8]; int n4; };

__global__ void f2b_multi(F2BJobs J){
  const float* __restrict__ src = J.s[blockIdx.y];
  u16* __restrict__ dst = J.d[blockIdx.y];
  int i = blockIdx.x*blockDim.x + threadIdx.x;
  if (i >= J.n4) return;
  float4 v = *(const float4*)(src + (size_t)i*4);
  ushort4 o; o.x=f2b(v.x); o.y=f2b(v.y); o.z=f2b(v.z); o.w=f2b(v.w);
  *(ushort4*)(dst + (size_t)i*4) = o;
}

// [S,B,H] fp32 -> [(b*S+s),H] bf16 (proj-GEMM A layout); blockIdx.y picks job
__global__ void remap2_kernel(const float* __restrict__ srcA, u16* __restrict__ dstA,
                              const float* __restrict__ srcB, u16* __restrict__ dstB){
  const float* __restrict__ src = blockIdx.y ? srcB : srcA;
  u16* __restrict__ dst = blockIdx.y ? dstB : dstA;
  int i = blockIdx.x*blockDim.x + threadIdx.x;     // over S*B*H/4
  if (i >= (S_LEN*BATCH*HDIM)/4) return;
  int elem = i*4;
  int s = elem >> 18;            // /(B*H)
  int b = (elem >> 9) & 511;
  int h = elem & 511;
  float4 v = *(const float4*)(src + (size_t)s*BATCH*HDIM + (size_t)b*HDIM + h);
  ushort4 o; o.x=f2b(v.x); o.y=f2b(v.y); o.z=f2b(v.z); o.w=f2b(v.w);
  *(ushort4*)(dst + ((size_t)b*S_LEN + s)*HDIM + h) = o;
}

// ---------------------------------------------------------------------------
// init: states + decoder inputs (bf16 activations, fp32 c), mask
// ---------------------------------------------------------------------------
__global__ void init_kernel(const float* __restrict__ h0, const float* __restrict__ c0,
                            const float* __restrict__ h0a, const float* __restrict__ c0a,
                            const float* __restrict__ dec, const unsigned char* __restrict__ vmask,
                            u16* __restrict__ h_bf, float* __restrict__ c_ws,
                            u16* __restrict__ x_bf, u16* __restrict__ xa_bf,
                            int* __restrict__ mask){
  for (int i = blockIdx.x*blockDim.x + threadIdx.x; i < BH; i += gridDim.x*blockDim.x) {
    h_bf[i]=f2b(h0[i]); h_bf[BH+i]=f2b(h0a[i]);
    c_ws[i]=c0[i];      c_ws[BH+i]=c0a[i];
    u16 d = f2b(dec[i]);
    x_bf[i]=d; xa_bf[i]=d;
    if (i < BS) mask[i] = vmask[i] ? 1 : 0;
  }
}

__global__ __launch_bounds__(64) void mask_fix_kernel(int* __restrict__ mask){
  int b = blockIdx.x, lane = threadIdx.x;
  int mv = (lane < S_LEN) ? mask[b*S_LEN+lane] : 1;
  unsigned long long bal = __ballot(mv != 0);
  if ((bal & MASK50) == MASK50 && lane == 49) mask[b*S_LEN+49] = 0;
}

// ---------------------------------------------------------------------------
// LSTM gate nonlinearity. g_ws: [0]=x*Wih^T [1]=h*Whh^T (main), [2],[3] aoi.
// Writes h as bf16 (GEMM operand), c as fp32.
// ---------------------------------------------------------------------------
__global__ void gates_kernel(const float* __restrict__ g_ws,
                             const float* __restrict__ b_ih, const float* __restrict__ b_hh,
                             const float* __restrict__ b_ih_a, const float* __restrict__ b_hh_a,
                             u16* __restrict__ h_bf, float* __restrict__ c_ws){
  int i = blockIdx.x*blockDim.x + threadIdx.x;          // over 2*BH
  if (i >= 2*BH) return;
  int z = i / BH, r = i % BH;
  int b = r >> 9, j = r & 511;
  const float* gA = g_ws + (size_t)(2*z+0)*BATCH*H4 + (size_t)b*H4;
  const float* gB = g_ws + (size_t)(2*z+1)*BATCH*H4 + (size_t)b*H4;
  const float* bi = z ? b_ih_a : b_ih;
  const float* bh = z ? b_hh_a : b_hh;
  float gi = gA[j]      + gB[j]      + bi[j]      + bh[j];
  float gf = gA[512+j]  + gB[512+j]  + bi[512+j]  + bh[512+j];
  float gg = gA[1024+j] + gB[1024+j] + bi[1024+j] + bh[1024+j];
  float go = gA[1536+j] + gB[1536+j] + bi[1536+j] + bh[1536+j];
  float cp = c_ws[i];
  float c2 = sigmoid_fast(gf)*cp + sigmoid_fast(gi)*tanh_fast(gg);
  float h2 = sigmoid_fast(go)*tanh_fast(c2);
  c_ws[i] = c2; h_bf[i] = f2b(h2);
}

// ---------------------------------------------------------------------------
// Glimpse attention + pointer-q: logits from e (pass 1), softmax, then
// q2 = bq_p + sum_s p_s * F[b,s,:] (pass 2 reads F -- same bytes as the old
// e re-read, but the output is the POINTER q, so the qp GEMM is gone).
// q from KSPQ fp32 partials + bq_g held in registers.
// ---------------------------------------------------------------------------
__global__ __launch_bounds__(512) void glimpse_kernel(
    const float* __restrict__ qpart,
    const float* __restrict__ bq_g, const float* __restrict__ bq_ga,
    const u16* __restrict__ e_g, const u16* __restrict__ e_ga,
    const float* __restrict__ v_g, const float* __restrict__ v_ga,
    const u16* __restrict__ F_m, const u16* __restrict__ F_a,
    const float* __restrict__ bq_p, const float* __restrict__ bq_pa,
    const int* __restrict__ mask, float* __restrict__ q2_ws){
  int z = blockIdx.y, b = blockIdx.x, tid = threadIdx.x;
  const u16* e = (z ? e_ga : e_g) + (size_t)b*S_LEN*HDIM;
  const float* v  = z ? v_ga : v_g;
  const float* bq = z ? bq_ga : bq_g;
  const float* qp = qpart + (size_t)z*KSPQ*BH + (size_t)b*HDIM;
  __shared__ float lg_sh[64], p_sh[64];
  int w = tid>>6, lane = tid&63;
  int h0 = lane*8;
  float qreg[8], vreg[8];
  #pragma unroll
  for (int ii=0; ii<8; ii++){
    int h = h0+ii;
    float q = bq[h];
    #pragma unroll
    for (int p=0;p<KSPQ;p++) q += qp[(size_t)p*BH + h];
    qreg[ii]=q; vreg[ii]=v[h];
  }
  for (int s = w; s < S_LEN; s += 8) {
    uint4 ev = *(const uint4*)(e + (size_t)s*HDIM + h0);
    const u16* pe = (const u16*)&ev;
    float acc = 0.0f;
    #pragma unroll
    for (int ii=0; ii<8; ii++) acc += vreg[ii]*tanh_fast(qreg[ii] + b2f(pe[ii]));
    acc = wave_sum(acc);
    if (lane==0) lg_sh[s] = mask[b*S_LEN+s] ? -INFINITY : acc;
  }
  __syncthreads();
  if (tid < 64) {
    float val = (tid < S_LEN) ? lg_sh[tid] : -INFINITY;
    float mx = wave_max(val);
    float ex = (tid < S_LEN) ? expf(val - mx) : 0.0f;
    float sm = wave_sum(ex);
    if (tid < S_LEN) p_sh[tid] = ex / sm;
  }
  __syncthreads();
  // q2 = bq_p + sum_s p_s * F[b,s,:]
  const u16* F = (z ? F_a : F_m) + (size_t)b*S_LEN*HDIM;
  float acc = (z ? bq_pa : bq_p)[tid];
  for (int s=0;s<S_LEN;s++) acc += p_sh[s]*b2f(F[(size_t)s*HDIM + tid]);
  q2_ws[(size_t)z*BH + (size_t)b*HDIM + tid] = acc;
}

// ---------------------------------------------------------------------------
// Fused pointer + combine + gather. One block per b, 512 thr = 8 waves;
// waves 0-3 z=0, waves 4-7 z=1. q2 read directly (fp32, bias included).
// Output clamps -inf -> -1e30.
// ---------------------------------------------------------------------------
__global__ __launch_bounds__(512) void pointer_combine_kernel(
    const float* __restrict__ q2_ws,
    const u16* __restrict__ e_p, const u16* __restrict__ e_pa,
    const float* __restrict__ v_p, const float* __restrict__ v_pa,
    int* __restrict__ mask,
    const u16* __restrict__ emb_bf, const u16* __restrict__ ench_bf,
    u16* __restrict__ x_bf, u16* __restrict__ xa_bf,
    float* __restrict__ out, int t){
  int b = blockIdx.x, tid = threadIdx.x;
  int w = tid>>6, lane = tid&63;
  int z = w>>2, wz = w&3;
  __shared__ float sh_lp[2][64];
  __shared__ int idx_sh;

  const u16* ep = (z ? e_pa : e_p) + (size_t)b*S_LEN*HDIM;
  const float* vp = z ? v_pa : v_p;
  int h0 = lane*8;
  float q2r[8], vpr[8];
  const float* q2g = q2_ws + (size_t)z*BH + (size_t)b*HDIM + h0;
  #pragma unroll
  for (int ii=0; ii<8; ii++){ q2r[ii]=q2g[ii]; vpr[ii]=vp[h0+ii]; }
  for (int s = wz; s < S_LEN; s += 4) {
    uint4 ev = *(const uint4*)(ep + (size_t)s*HDIM + h0);
    const u16* pe = (const u16*)&ev;
    float acc = 0.0f;
    #pragma unroll
    for (int ii=0; ii<8; ii++) acc += vpr[ii]*tanh_fast(q2r[ii] + b2f(pe[ii]));
    acc = wave_sum(acc);
    if (lane==0) sh_lp[z][s] = mask[b*S_LEN+s] ? -INFINITY : 10.0f*tanh_fast(acc);
  }
  __syncthreads();

  if (tid < 64) {
    float a  = (lane < S_LEN) ? sh_lp[0][lane] : -INFINITY;
    float ca = (lane < S_LEN) ? sh_lp[1][lane] : -INFINITY;
    float m1 = wave_max(a);
    float l1 = logf(wave_sum((lane < S_LEN) ? expf(a - m1) : 0.0f));
    float m2 = wave_max(ca);
    float l2 = logf(wave_sum((lane < S_LEN) ? expf(ca - m2) : 0.0f));
    float logp = (a - m1 - l1) + 0.1f * (ca - m2 - l2);
    if (lane < S_LEN) out[(size_t)b*(S_LEN*S_LEN) + t*S_LEN + lane] = fmaxf(logp, -1e30f);
    float vv = (lane < S_LEN) ? logp : -INFINITY;
    int bi = lane;
    #pragma unroll
    for (int o=32;o;o>>=1) {
      float ov = __shfl_xor(vv, o); int oi = __shfl_xor(bi, o);
      if (ov > vv || (ov == vv && oi < bi)) { vv = ov; bi = oi; }
    }
    int idx = bi;
    if (lane == 0) { out[(size_t)BATCH*S_LEN*S_LEN + b*S_LEN + t] = (float)idx; idx_sh = idx; }
    int mv = 1;
    if (lane < S_LEN) { mv = mask[b*S_LEN+lane]; if (lane==idx) mv = 1; mask[b*S_LEN+lane] = mv; }
    unsigned long long bal = __ballot(mv != 0);
    if ((bal & MASK50) == MASK50 && lane == 49) mask[b*S_LEN+49] = 0;
  }
  __syncthreads();

  int idx = idx_sh;
  x_bf[(size_t)b*HDIM + tid]  = emb_bf[((size_t)idx*BATCH + b)*HDIM + tid];
  xa_bf[(size_t)b*HDIM + tid] = ench_bf[((size_t)idx*BATCH + b)*HDIM + tid];
}

// ---------------------------------------------------------------------------
extern "C" void kernel_launch(void* const* d_in, const int* in_sizes, int n_in,
                              void* d_out, int out_size, void* d_ws, size_t ws_size,
                              hipStream_t stream) {
  (void)in_sizes; (void)n_in; (void)out_size; (void)ws_size;
  const float* dec    = (const float*)d_in[0];
  const float* emb    = (const float*)d_in[1];
  const float* h0     = (const float*)d_in[2];
  const float* c0     = (const float*)d_in[3];
  const float* ctx    = (const float*)d_in[4];
  const float* ench   = (const float*)d_in[5];
  const float* dia    = (const float*)d_in[6];
  const float* h0a    = (const float*)d_in[7];
  const float* c0a    = (const float*)d_in[8];
  const unsigned char* vmask = (const unsigned char*)d_in[9];
  const float* W_ih   = (const float*)d_in[10];
  const float* W_hh   = (const float*)d_in[11];
  const float* b_ih   = (const float*)d_in[12];
  const float* b_hh   = (const float*)d_in[13];
  const float* W_ih_a = (const float*)d_in[14];
  const float* W_hh_a = (const float*)d_in[15];
  const float* b_ih_a = (const float*)d_in[16];
  const float* b_hh_a = (const float*)d_in[17];
  const float* Wq_p  = (const float*)d_in[18];
  const float* bq_p  = (const float*)d_in[19];
  const float* Wr_p  = (const float*)d_in[20];
  const float* br_p  = (const float*)d_in[21];
  const float* v_p   = (const float*)d_in[22];
  const float* Wq_pa = (const float*)d_in[23];
  const float* bq_pa = (const float*)d_in[24];
  const float* Wr_pa = (const float*)d_in[25];
  const float* br_pa = (const float*)d_in[26];
  const float* v_pa  = (const float*)d_in[27];
  const float* Wq_g  = (const float*)d_in[28];
  const float* bq_g  = (const float*)d_in[29];
  const float* Wr_g  = (const float*)d_in[30];
  const float* br_g  = (const float*)d_in[31];
  const float* v_g   = (const float*)d_in[32];
  const float* Wq_ga = (const float*)d_in[33];
  const float* bq_ga = (const float*)d_in[34];
  const float* Wr_ga = (const float*)d_in[35];
  const float* br_ga = (const float*)d_in[36];
  const float* v_ga  = (const float*)d_in[37];

  char* base = (char*)d_ws;
  size_t off = 0;
  auto carve = [&](size_t bytes)->char*{ char* p = base + off; off += (bytes + 255) & ~(size_t)255; return p; };

  const size_t E_BYTES = (size_t)BS*HDIM*2;      // 26,214,400
  u16* e_g   = (u16*)carve(E_BYTES);
  u16* e_p   = (u16*)carve(E_BYTES);
  u16* e_ga  = (u16*)carve(E_BYTES);
  u16* e_pa  = (u16*)carve(E_BYTES);
  u16* F_m   = (u16*)carve(E_BYTES);             // e_g  @ Wq_p^T  (hoisted)
  u16* F_a   = (u16*)carve(E_BYTES);             // e_ga @ Wq_pa^T
  char* scratch = carve(2*E_BYTES);              // A_ctx/A_dia, later emb/ench bf16
  u16* A_ctx  = (u16*)scratch;
  u16* A_dia  = (u16*)(scratch + E_BYTES);
  u16* emb_bf  = A_ctx;                          // aliases (prologue-ordered)
  u16* ench_bf = A_dia;
  u16* Wih_bf  = (u16*)carve((size_t)H4*HDIM*2);
  u16* Whh_bf  = (u16*)carve((size_t)H4*HDIM*2);
  u16* Wiha_bf = (u16*)carve((size_t)H4*HDIM*2);
  u16* Whha_bf = (u16*)carve((size_t)H4*HDIM*2);
  u16* Wqg_bf  = (u16*)carve((size_t)BH*2);      // 512x512
  u16* Wqga_bf = (u16*)carve((size_t)BH*2);
  u16* Wqp_bf  = (u16*)carve((size_t)BH*2);
  u16* Wqpa_bf = (u16*)carve((size_t)BH*2);
  u16* Wrg_bf  = (u16*)carve((size_t)BH*2);
  u16* Wrp_bf  = (u16*)carve((size_t)BH*2);
  u16* Wrga_bf = (u16*)carve((size_t)BH*2);
  u16* Wrpa_bf = (u16*)carve((size_t)BH*2);
  u16* x_bf    = (u16*)carve((size_t)BH*2);
  u16* xa_bf   = (u16*)carve((size_t)BH*2);
  u16* h_bf    = (u16*)carve((size_t)2*BH*2);    // [2][B][H]
  float* c_ws  = (float*)carve((size_t)2*BH*4);
  float* g_ws  = (float*)carve((size_t)4*BATCH*H4*4);
  float* q_ws  = (float*)carve((size_t)2*KSPQ*BH*4);
  float* q2_ws = (float*)carve((size_t)2*BH*4);  // direct q2 (no split-K)
  int*   mask  = (int*)carve((size_t)BS*4);
  float* out   = (float*)d_out;

  init_kernel<<<1024, 256, 0, stream>>>(h0, c0, h0a, c0a, dec, vmask,
                                        h_bf, c_ws, x_bf, xa_bf, mask);
  mask_fix_kernel<<<BATCH, 64, 0, stream>>>(mask);

  // --- prologue conversions (batched) ---
  const int RB = ((S_LEN*BATCH*HDIM/4)+255)/256;
  remap2_kernel<<<dim3(RB,2), 256, 0, stream>>>(ctx, A_ctx, dia, A_dia);

  const int NW4 = H4*HDIM/4, NWQ = BH/4;
  F2BJobs jw{};   // 4 LSTM weight matrices [2048x512]
  jw.s[0]=W_ih; jw.d[0]=Wih_bf;  jw.s[1]=W_hh; jw.d[1]=Whh_bf;
  jw.s[2]=W_ih_a; jw.d[2]=Wiha_bf; jw.s[3]=W_hh_a; jw.d[3]=Whha_bf;
  jw.n4 = NW4;
  f2b_multi<<<dim3((NW4+255)/256,4), 256, 0, stream>>>(jw);

  F2BJobs jq{};   // 8 attention weight matrices [512x512]
  jq.s[0]=Wq_g;  jq.d[0]=Wqg_bf;  jq.s[1]=Wq_ga; jq.d[1]=Wqga_bf;
  jq.s[2]=Wq_p;  jq.d[2]=Wqp_bf;  jq.s[3]=Wq_pa; jq.d[3]=Wqpa_bf;
  jq.s[4]=Wr_g;  jq.d[4]=Wrg_bf;  jq.s[5]=Wr_p;  jq.d[5]=Wrp_bf;
  jq.s[6]=Wr_ga; jq.d[6]=Wrga_bf; jq.s[7]=Wr_pa; jq.d[7]=Wrpa_bf;
  jq.n4 = NWQ;
  f2b_multi<<<dim3((NWQ+255)/256,8), 256, 0, stream>>>(jq);

  // Hoisted context projections -> e (bf16, [B,S,H] row = b*S+s)
  MArgs pa{};
  pa.A[0]=A_ctx; pa.A[1]=A_ctx; pa.A[2]=A_dia; pa.A[3]=A_dia;
  pa.W[0]=Wrg_bf; pa.W[1]=Wrp_bf; pa.W[2]=Wrga_bf; pa.W[3]=Wrpa_bf;
  pa.bias[0]=br_g; pa.bias[1]=br_p; pa.bias[2]=br_ga; pa.bias[3]=br_pa;
  pa.C[0]=e_g; pa.C[1]=e_p; pa.C[2]=e_ga; pa.C[3]=e_pa;
  pa.M=BS; pa.N=HDIM; pa.K=HDIM; pa.lda=HDIM; pa.ksplit=1; pa.out_bf16=1;
  mfma_gemm<<<dim3(4,200,4), 256, 0, stream>>>(pa);

  // F = e_g @ Wq_p^T (and aoi): pointer-q projection hoisted by linearity
  MArgs fa{};
  fa.A[0]=e_g; fa.A[1]=e_ga;
  fa.W[0]=Wqp_bf; fa.W[1]=Wqpa_bf;
  fa.bias[0]=fa.bias[1]=nullptr;
  fa.C[0]=F_m; fa.C[1]=F_a;
  fa.M=BS; fa.N=HDIM; fa.K=HDIM; fa.lda=HDIM; fa.ksplit=1; fa.out_bf16=1;
  mfma_gemm<<<dim3(4,200,2), 256, 0, stream>>>(fa);

  // emb/ench bf16 copies into the (now dead) A_ctx/A_dia space
  const int NE = S_LEN*BATCH*HDIM/4;
  F2BJobs je{};
  je.s[0]=emb; je.d[0]=emb_bf; je.s[1]=ench; je.d[1]=ench_bf;
  je.n4 = NE;
  f2b_multi<<<dim3((NE+255)/256,2), 256, 0, stream>>>(je);

  // --- per-step GEMM arg sets ---
  MArgs la{};
  la.A[0]=x_bf; la.A[1]=h_bf; la.A[2]=xa_bf; la.A[3]=h_bf+BH;
  la.W[0]=Wih_bf; la.W[1]=Whh_bf; la.W[2]=Wiha_bf; la.W[3]=Whha_bf;
  la.bias[0]=la.bias[1]=la.bias[2]=la.bias[3]=nullptr;
  la.C[0]=g_ws; la.C[1]=g_ws+(size_t)BATCH*H4; la.C[2]=g_ws+2*(size_t)BATCH*H4; la.C[3]=g_ws+3*(size_t)BATCH*H4;
  la.M=BATCH; la.N=H4; la.K=HDIM; la.lda=HDIM; la.ksplit=1; la.out_bf16=0;

  MArgs qg{};
  qg.A[0]=h_bf; qg.A[1]=h_bf+BH;
  qg.W[0]=Wqg_bf; qg.W[1]=Wqga_bf;
  qg.bias[0]=qg.bias[1]=qg.bias[2]=qg.bias[3]=nullptr;
  qg.C[0]=q_ws; qg.C[1]=q_ws+(size_t)KSPQ*BH;
  qg.M=BATCH; qg.N=HDIM; qg.K=HDIM; qg.lda=HDIM; qg.ksplit=KSPQ; qg.out_bf16=0;

  for (int t = 0; t < S_LEN; ++t) {
    mfma_gemm<<<dim3(16,4,4), 256, 0, stream>>>(la);
    gates_kernel<<<(2*BH+255)/256, 256, 0, stream>>>(g_ws, b_ih, b_hh, b_ih_a, b_hh_a, h_bf, c_ws);
    mfma_gemm<<<dim3(4,4*KSPQ,2), 256, 0, stream>>>(qg);
    glimpse_kernel<<<dim3(BATCH,2), 512, 0, stream>>>(
        q_ws, bq_g, bq_ga, e_g, e_ga, v_g, v_ga,
        F_m, F_a, bq_p, bq_pa, mask, q2_ws);
    pointer_combine_kernel<<<BATCH, 512, 0, stream>>>(
        q2_ws, e_p, e_pa, v_p, v_pa,
        mask, emb_bf, ench_bf, x_bf, xa_bf, out, t);
  }
}